// Round 4
// baseline (795.308 us; speedup 1.0000x reference)
//
#include <hip/hip_runtime.h>

typedef short short8 __attribute__((ext_vector_type(8)));
typedef short short4v __attribute__((ext_vector_type(4)));
typedef float f32x4 __attribute__((ext_vector_type(4)));

#define T_SEQ 2048
#define C_DIM 2048
#define H_NUM 16
#define D_HEAD 128
#define B_NUM 4
#define M_ROWS (B_NUM * T_SEQ)   // 8192

__device__ __forceinline__ unsigned short f2bf(float f) {
    union { float f; unsigned u; } v; v.f = f;
    unsigned r = v.u + 0x7FFFu + ((v.u >> 16) & 1u);
    return (unsigned short)(r >> 16);
}
__device__ __forceinline__ float bf2f(unsigned short u) {
    union { unsigned u; float f; } v; v.u = ((unsigned)u) << 16;
    return v.f;
}

// async global->LDS, 16B per lane; lds ptr wave-uniform (HW adds lane*16)
__device__ __forceinline__ void async_ld16(const unsigned short* g, unsigned short* l) {
    __builtin_amdgcn_global_load_lds(
        (const __attribute__((address_space(1))) unsigned int*)g,
        (__attribute__((address_space(3))) unsigned int*)l,
        16, 0, 0);
}

__device__ __forceinline__ f32x4 pv_mfma(short4v v, short4v p, f32x4 c) {
#if __has_builtin(__builtin_amdgcn_mfma_f32_16x16x16bf16_1k)
    return __builtin_amdgcn_mfma_f32_16x16x16bf16_1k(v, p, c, 0, 0, 0);
#else
    short8 vf = {v[0], v[1], v[2], v[3], 0, 0, 0, 0};
    short8 pf = {p[0], p[1], p[2], p[3], 0, 0, 0, 0};
    return __builtin_amdgcn_mfma_f32_16x16x32_bf16(vf, pf, c, 0, 0, 0);
#endif
}

// ---------------- weight cast + transpose: wt[w][n][k] = W_w[k][n] (bf16) ----
__global__ __launch_bounds__(256) void wcast_kernel(const float* __restrict__ W0,
                                                    const float* __restrict__ W1,
                                                    const float* __restrict__ W2,
                                                    const float* __restrict__ W3,
                                                    unsigned short* __restrict__ wt) {
    __shared__ float tile[32][33];
    const float* W = (blockIdx.z == 0) ? W0 : (blockIdx.z == 1) ? W1 : (blockIdx.z == 2) ? W2 : W3;
    unsigned short* out = wt + (size_t)blockIdx.z * C_DIM * C_DIM;
    int tx = threadIdx.x, ty = threadIdx.y;      // block (32, 8)
    int n0 = blockIdx.x * 32, k0 = blockIdx.y * 32;
    #pragma unroll
    for (int j = 0; j < 32; j += 8)
        tile[ty + j][tx] = W[(size_t)(k0 + ty + j) * C_DIM + n0 + tx];
    __syncthreads();
    #pragma unroll
    for (int j = 0; j < 32; j += 8)
        out[(size_t)(n0 + ty + j) * C_DIM + k0 + tx] = f2bf(tile[tx][ty + j]);
}

// ---------------- LayerNorm -> bf16 ----------------------------------------
__global__ __launch_bounds__(256) void ln_kernel(const float* __restrict__ x,
                                                 const float* __restrict__ g,
                                                 const float* __restrict__ bta,
                                                 unsigned short* __restrict__ nx) {
    int row = blockIdx.x;
    int tid = threadIdx.x;
    const float* xr = x + (size_t)row * C_DIM;
    float4 v0 = *(const float4*)(xr + tid * 8);
    float4 v1 = *(const float4*)(xr + tid * 8 + 4);
    float s = v0.x + v0.y + v0.z + v0.w + v1.x + v1.y + v1.z + v1.w;
    float q = v0.x * v0.x + v0.y * v0.y + v0.z * v0.z + v0.w * v0.w +
              v1.x * v1.x + v1.y * v1.y + v1.z * v1.z + v1.w * v1.w;
    #pragma unroll
    for (int m = 32; m; m >>= 1) { s += __shfl_xor(s, m); q += __shfl_xor(q, m); }
    __shared__ float red[2][4];
    int wave = tid >> 6, lane = tid & 63;
    if (lane == 0) { red[0][wave] = s; red[1][wave] = q; }
    __syncthreads();
    s = red[0][0] + red[0][1] + red[0][2] + red[0][3];
    q = red[1][0] + red[1][1] + red[1][2] + red[1][3];
    float mu = s * (1.0f / C_DIM);
    float var = q * (1.0f / C_DIM) - mu * mu;
    float rstd = rsqrtf(var + 1e-5f);
    float4 g0 = *(const float4*)(g + tid * 8);
    float4 g1 = *(const float4*)(g + tid * 8 + 4);
    float4 b0 = *(const float4*)(bta + tid * 8);
    float4 b1 = *(const float4*)(bta + tid * 8 + 4);
    unsigned short o[8];
    o[0] = f2bf((v0.x - mu) * rstd * g0.x + b0.x);
    o[1] = f2bf((v0.y - mu) * rstd * g0.y + b0.y);
    o[2] = f2bf((v0.z - mu) * rstd * g0.z + b0.z);
    o[3] = f2bf((v0.w - mu) * rstd * g0.w + b0.w);
    o[4] = f2bf((v1.x - mu) * rstd * g1.x + b1.x);
    o[5] = f2bf((v1.y - mu) * rstd * g1.y + b1.y);
    o[6] = f2bf((v1.z - mu) * rstd * g1.z + b1.z);
    o[7] = f2bf((v1.w - mu) * rstd * g1.w + b1.w);
    uint4 pk;
    pk.x = (unsigned)o[0] | ((unsigned)o[1] << 16);
    pk.y = (unsigned)o[2] | ((unsigned)o[3] << 16);
    pk.z = (unsigned)o[4] | ((unsigned)o[5] << 16);
    pk.w = (unsigned)o[6] | ((unsigned)o[7] << 16);
    *(uint4*)(nx + (size_t)row * C_DIM + tid * 8) = pk;
}

// ============================================================================
// 256x256 / BK=64 / 8-wave GEMM core, A-in-LDS + B-DIRECT-TO-REGISTER.
//
// Round-3 diagnosis: MFMA-pipe-busy (MfmaUtil x tile-time) == MFMA floor, so
// the pipe had no bubbles; the extra ~3400cy/tile was the LDS pipe (192KB
// reads + 64KB DMA writes ~ 2800cy) serialized against it. B has ZERO
// intra-block reuse (each wave owns disjoint N-columns), so B-LDS staging
// was pure overhead: -64KB ds_read, -32KB DMA per tile by loading B frags
// global->VGPR directly (per-lane 16B = exact MFMA B layout).
//
// LDS (dynamic, 64 KiB): 2 buffers x A[256][64] bf16 (Ah0 @0, Ah1 @8192 elems).
//   XOR chunk swizzle on A: 16B-chunk c of row r at slot c^(r&7); global
//   source pre-swizzled (global_load_lds dest is linear).
// Per tile t (A from buf[t&1]; B in loop-carried regs cb0/cb1 loaded at the
// end of tile t-1):
//   RDA(qm0); c1 af*cb0 -> acc00; c2 af*cb1 -> acc01; RDA(qm1);
//   BAR#1  (fences all waves' A(t) read issue before the t+2 stage below)
//   c3 af*cb1 -> acc11; c4 af*cb0 -> acc10;
//   LOADB(t+1) -> cb0/cb1 (8 global loads; WAR-safe: after c3/c4);
//   STAGE A(t+2) -> buf[t&1] (4 DMA ops; lands >=300cy after BAR#1);
//   vmcnt(12); BAR#2.
// vmcnt algebra (per wave, in-order retire): outstanding at boundary =
//   A(t+1)(4, issued t-1 end) + B(t+1)(8) + A(t+2)(4) = 16; vmcnt(12)
//   retires exactly A(t+1) -> tile t+1's A resident (compiler cannot track
//   DMA->ds_read hazards; this wait is REQUIRED). Compiler's own waits
//   before c1/c2 retire only the B set (older ops already retired) -> no
//   mid-loop drain. B loads have ~1 tile (>3000cy) of latency slack.
// ============================================================================

#define GBK 64
#define GNT (C_DIM / GBK)        // 32 K-tiles

#define GFENCE __asm__ volatile("" ::: "memory")
#define GBAR do { GFENCE; __builtin_amdgcn_s_barrier(); GFENCE; } while (0)

__device__ __forceinline__ void mfma16(const short8 af[4][2], const short8 bf[2][2],
                                       f32x4 acc[4][2]) {
    __builtin_amdgcn_s_setprio(1);
    #pragma unroll
    for (int mi = 0; mi < 4; mi++)
        #pragma unroll
        for (int ni = 0; ni < 2; ni++)
            #pragma unroll
            for (int ks = 0; ks < 2; ks++)
                acc[mi][ni] = __builtin_amdgcn_mfma_f32_16x16x32_bf16(af[mi][ks], bf[ni][ks],
                                                                      acc[mi][ni], 0, 0, 0);
    __builtin_amdgcn_s_setprio(0);
}

__device__ __forceinline__ void gemm_core256(const unsigned short* __restrict__ A,
                                             const unsigned short* __restrict__ Bt,
                                             unsigned short* lds,
                                             int rowBase, int colBase,
                                             f32x4 acc[2][2][4][2]) {
    const int tid = threadIdx.x;
    const int lane = tid & 63, w = tid >> 6;
    const int quad = lane >> 4, lo = lane & 15;
    const int wm = w >> 2, wn = w & 3;

    // A LDS read base (elements)
    const int swz8 = (quad ^ (lo & 7)) * 8;
    const int aoff = (wm * 64 + lo) * 64 + swz8;

    // A staging: per-lane pre-swizzled global offsets + wave-uniform LDS dests
    const int r8 = lane >> 3, c8 = lane & 7;
    const int goff0 = (w * 8 + r8) * C_DIM + ((c8 ^ r8) << 3);
    const int goff1 = (64 + w * 8 + r8) * C_DIM + ((c8 ^ r8) << 3);
    const int ldst0 = (w * 8) * 64;
    const int ldst1 = (64 + w * 8) * 64;

    unsigned short* const L0 = lds;            // buf0: 16384 elems (32 KB)
    unsigned short* const L1 = lds + 16384;    // buf1

    const unsigned short* gA0 = A + (size_t)rowBase * C_DIM;
    const unsigned short* gA1 = gA0 + (size_t)128 * C_DIM;
    // B direct-load bases: lane covers row (wn*32 + ni*16 + lo), k-chunk quad*8
    const unsigned short* gBq0 = Bt + ((size_t)(colBase + wn * 32 + lo)) * C_DIM + quad * 8;
    const unsigned short* gBq1 = gBq0 + (size_t)128 * C_DIM;

#define STAGE(gbase, lregion) do { \
        async_ld16((gbase) + goff0, (lregion) + ldst0); \
        async_ld16((gbase) + goff1, (lregion) + ldst1); \
    } while (0)

#define RDA(As, qm, dst) do { \
        _Pragma("unroll") \
        for (int mi = 0; mi < 4; mi++) { \
            dst[mi][0] = *(const short8*)((As) + (((qm) * 8192 + mi * 1024 + aoff))); \
            dst[mi][1] = *(const short8*)((As) + (((qm) * 8192 + mi * 1024 + aoff) ^ 32)); \
        } \
    } while (0)

    // frag (qn, ni, ks) from global: gBq[qn] + ni*16*C_DIM + t*GBK + ks*32
#define LOADB(tt) do { \
        const unsigned short* _b0 = gBq0 + (tt) * GBK; \
        const unsigned short* _b1 = gBq1 + (tt) * GBK; \
        cb0[0][0] = *(const short8*)(_b0); \
        cb0[0][1] = *(const short8*)(_b0 + 32); \
        cb0[1][0] = *(const short8*)(_b0 + 16 * C_DIM); \
        cb0[1][1] = *(const short8*)(_b0 + 16 * C_DIM + 32); \
        cb1[0][0] = *(const short8*)(_b1); \
        cb1[0][1] = *(const short8*)(_b1 + 32); \
        cb1[1][0] = *(const short8*)(_b1 + 16 * C_DIM); \
        cb1[1][1] = *(const short8*)(_b1 + 16 * C_DIM + 32); \
    } while (0)

    short8 cb0[2][2], cb1[2][2];

    // prologue: B(0) 8 loads, A(0) 4 DMA, A(1) 4 DMA -> 16 outstanding;
    // vmcnt(4) retires B(0)+A(0), keeps A(1) in flight.
    LOADB(0);
    STAGE(gA0, L0); STAGE(gA1, L0 + 8192);             // A(0)
    STAGE(gA0 + GBK, L1); STAGE(gA1 + GBK, L1 + 8192); // A(1)
    __builtin_amdgcn_s_waitcnt(0x3F74);                // vmcnt(4)
    GBAR;

    for (int t = 0; t < GNT; ++t) {
        const unsigned short* As = (t & 1) ? L1 : L0;
        unsigned short* Lc = (t & 1) ? L1 : L0;        // stage target buf[t&1] (for t+2)
        short8 af[4][2];

        RDA(As, 0, af);
        mfma16(af, cb0, acc[0][0]);
        mfma16(af, cb1, acc[0][1]);
        RDA(As, 1, af);
        GBAR;                                          // BAR#1

        mfma16(af, cb1, acc[1][1]);
        mfma16(af, cb0, acc[1][0]);
        if (t + 1 < GNT) LOADB(t + 1);                 // 8 loads (after last cb use)
        if (t + 2 < GNT) {                             // 4 DMA ops
            STAGE(gA0 + (t + 2) * GBK, Lc);
            STAGE(gA1 + (t + 2) * GBK, Lc + 8192);
        }
        __builtin_amdgcn_s_waitcnt(0x3F7C);            // vmcnt(12): A(t+1) resident
        GBAR;                                          // BAR#2
    }
#undef STAGE
#undef RDA
#undef LOADB
}

// ---------------- fused QKV GEMM (N = 6144) ---------------------------------
__global__ __launch_bounds__(512, 2) void gemm_qkv(const unsigned short* __restrict__ A,
                                                   const unsigned short* __restrict__ Bt,
                                                   const float* __restrict__ bq,
                                                   const float* __restrict__ bk,
                                                   const float* __restrict__ bv,
                                                   unsigned short* __restrict__ qb,
                                                   unsigned short* __restrict__ kb,
                                                   unsigned short* __restrict__ vtb) {
    extern __shared__ unsigned short ldsbuf[];
    f32x4 acc[2][2][4][2] = {};
    const int bid = blockIdx.x;                   // 768 blocks, 768%8==0
    const int b2 = (bid & 7) * 96 + (bid >> 3);   // bijective XCD swizzle
    const int rowBase = (b2 / 24) * 256;
    const int colBase = (b2 % 24) * 256;
    gemm_core256(A, Bt, ldsbuf, rowBase, colBase, acc);

    const int lane = threadIdx.x & 63, w = threadIdx.x >> 6;
    const int quad = lane >> 4, lo = lane & 15;
    const int wm = w >> 2, wn = w & 3;
    const int which = colBase >> 11;              // 256-tiles never straddle 2048
    const float* bias = (which == 0) ? bq : (which == 1) ? bk : bv;
    #pragma unroll
    for (int qm = 0; qm < 2; qm++)
        #pragma unroll
        for (int qn = 0; qn < 2; qn++)
            #pragma unroll
            for (int mi = 0; mi < 4; mi++)
                #pragma unroll
                for (int ni = 0; ni < 2; ni++) {
                    int n = colBase + qn * 128 + wn * 32 + ni * 16 + lo;
                    int c = n & (C_DIM - 1), h = c >> 7, d = c & 127;
                    float bsv = bias[c];
                    #pragma unroll
                    for (int r = 0; r < 4; r++) {
                        int m = rowBase + qm * 128 + wm * 64 + mi * 16 + quad * 4 + r;
                        int bb = m >> 11, tt = m & (T_SEQ - 1);
                        unsigned short u = f2bf(acc[qm][qn][mi][ni][r] + bsv);
                        if (which == 2)
                            vtb[(size_t)((bb * H_NUM + h) * D_HEAD + d) * T_SEQ + tt] = u;
                        else if (which == 1)
                            kb[(size_t)((bb * H_NUM + h) * T_SEQ + tt) * D_HEAD + d] = u;
                        else
                            qb[(size_t)((bb * H_NUM + h) * T_SEQ + tt) * D_HEAD + d] = u;
                    }
                }
}

// ---------------- output GEMM + bias + residual -----------------------------
__global__ __launch_bounds__(512, 2) void gemm_out(const unsigned short* __restrict__ A,
                                                   const unsigned short* __restrict__ Bt,
                                                   const float* __restrict__ bo,
                                                   const float* __restrict__ x,
                                                   float* __restrict__ out) {
    extern __shared__ unsigned short ldsbuf[];
    f32x4 acc[2][2][4][2] = {};
    const int bid = blockIdx.x;                   // 256 blocks
    const int b2 = (bid & 7) * 32 + (bid >> 3);
    const int rowBase = (b2 / 8) * 256;
    const int colBase = (b2 % 8) * 256;
    gemm_core256(A, Bt, ldsbuf, rowBase, colBase, acc);

    const int lane = threadIdx.x & 63, w = threadIdx.x >> 6;
    const int quad = lane >> 4, lo = lane & 15;
    const int wm = w >> 2, wn = w & 3;
    #pragma unroll
    for (int qm = 0; qm < 2; qm++)
        #pragma unroll
        for (int qn = 0; qn < 2; qn++)
            #pragma unroll
            for (int mi = 0; mi < 4; mi++)
                #pragma unroll
                for (int ni = 0; ni < 2; ni++) {
                    int n = colBase + qn * 128 + wn * 32 + ni * 16 + lo;
                    float bsv = bo[n];
                    #pragma unroll
                    for (int r = 0; r < 4; r++) {
                        int m = rowBase + qm * 128 + wm * 64 + mi * 16 + quad * 4 + r;
                        size_t idx = (size_t)m * C_DIM + n;
                        out[idx] = x[idx] + acc[qm][qn][mi][ni][r] + bsv;
                    }
                }
}

// ---------------- RoPE (in-place, bf16) -------------------------------------
__global__ __launch_bounds__(256) void rope_kernel(unsigned short* __restrict__ qb,
                                                   unsigned short* __restrict__ kb) {
    const bool isk = (blockIdx.y != 0);
    unsigned short* p = isk ? kb : qb;
    const float osc = isk ? 1.0f : 0.12751736f;    // log2(e)/sqrt(128)
    int pidx = blockIdx.x * 256 + threadIdx.x;     // 0 .. B*H*T*64-1
    int dd = pidx & 63;
    int bht = pidx >> 6;
    int t = bht & (T_SEQ - 1);
    unsigned short* base = p + (size_t)bht * D_HEAD;
    float x0 = bf2f(base[dd]);
    float x1 = bf2f(base[dd + 64]);
    float inv = exp2f((float)dd * (-13.287712379549449f / 64.0f));  // 10000^(-dd/64)
    float ang = (float)t * inv;
    float sn = __sinf(ang), cs = __cosf(ang);
    base[dd]      = f2bf((x0 * cs - x1 * sn) * osc);
    base[dd + 64] = f2bf((x1 * cs + x0 * sn) * osc);
}

// ---------------- causal flash attention (v4, unchanged) ---------------------
__device__ __forceinline__ void attn_stage(const unsigned short* __restrict__ kh,
                                           const unsigned short* __restrict__ vh,
                                           int kt, unsigned short* Kd, unsigned short* Vd,
                                           int w, int lane) {
    const int l4 = lane >> 4, c16 = lane & 15;
    const int l8 = lane >> 3, c8 = lane & 7;
    #pragma unroll
    for (int j = 0; j < 2; j++) {
        int R = w * 8 + j * 4;                     // K rows R..R+3
        int row = R + l4;
        int cl = c16 ^ (row & 15);                 // LDS slot (row,cs) holds chunk cs^row15
        async_ld16(kh + (size_t)(kt * 64 + row) * D_HEAD + cl * 8, Kd + R * D_HEAD);
    }
    #pragma unroll
    for (int j = 0; j < 2; j++) {
        int o8 = w * 2 + j;                        // V 8-row chunk 0..15
        int row = o8 * 8 + l8;
        int gu = (2 * c8) ^ (row & 14);            // 8B-unit swizzle, even mask keeps pairs
        async_ld16(vh + (size_t)row * T_SEQ + kt * 64 + gu * 4, Vd + o8 * 512);
    }
}

__device__ __forceinline__ void attn_tile128(const unsigned short* __restrict__ qh,
                                             const unsigned short* __restrict__ kh,
                                             const unsigned short* __restrict__ vh,
                                             unsigned short* __restrict__ attn_out,
                                             int tile, int b, int h, int w, int quad,
                                             int lo, int lane,
                                             unsigned short* Kb, unsigned short* Vb) {
    const int G = tile * 128 + 16 * w;           // this wave's 16 q-rows
    const int a = (G + 15) >> 6;                 // last needed k-tile
    const int nkt = 2 * tile + 2;
    const int tq = G + lo;

    short8 qf[4];
    #pragma unroll
    for (int ks = 0; ks < 4; ks++)
        qf[ks] = *(const short8*)(qh + (size_t)(G + lo) * D_HEAD + ks * 32 + quad * 8);

    float m_i = -1e30f, l_i = 0.f;
    f32x4 o[8];
    #pragma unroll
    for (int dt = 0; dt < 8; dt++) o[dt] = (f32x4){0.f, 0.f, 0.f, 0.f};

    attn_stage(kh, vh, 0, Kb, Vb, w, lane);
    for (int kt = 0; kt < nkt; kt++) {
        const int cur = kt & 1;
        if (kt + 1 < nkt) {
            attn_stage(kh, vh, kt + 1, Kb + (cur ^ 1) * 8192, Vb + (cur ^ 1) * 8192, w, lane);
            __builtin_amdgcn_s_waitcnt(0x3F74);   // vmcnt(4): this tile's 4 loads done
        } else {
            __builtin_amdgcn_s_waitcnt(0x3F70);   // vmcnt(0)
        }
        __asm__ volatile("" ::: "memory");
        __builtin_amdgcn_s_barrier();
        __asm__ volatile("" ::: "memory");

        if (kt <= a) {                            // wave-uniform
            const unsigned short* Kc = Kb + cur * 8192;
            const unsigned short* Vc = Vb + cur * 8192;
            // QK: S^T[key][qrow] = K . Q^T
            f32x4 s[4];
            #pragma unroll
            for (int kg = 0; kg < 4; kg++) s[kg] = (f32x4){0.f, 0.f, 0.f, 0.f};
            #pragma unroll
            for (int kg = 0; kg < 4; kg++)
                #pragma unroll
                for (int ks = 0; ks < 4; ks++) {
                    int ch = (ks * 4 + quad) ^ lo;            // row&15 == lo
                    short8 kf = *(const short8*)(Kc + (kg * 16 + lo) * D_HEAD + ch * 8);
                    s[kg] = __builtin_amdgcn_mfma_f32_16x16x32_bf16(kf, qf[ks], s[kg], 0, 0, 0);
                }

            // online softmax (exp2 domain; scale folded into Q)
            const bool msk = (kt == a);
            float mx = -1e30f;
            #pragma unroll
            for (int kg = 0; kg < 4; kg++)
                #pragma unroll
                for (int r = 0; r < 4; r++) {
                    if (msk) {
                        int key = kt * 64 + kg * 16 + quad * 4 + r;
                        if (key > tq) s[kg][r] = -1e30f;
                    }
                    mx = fmaxf(mx, s[kg][r]);
                }
            mx = fmaxf(mx, __shfl_xor(mx, 16));
            mx = fmaxf(mx, __shfl_xor(mx, 32));
            float mnew = fmaxf(m_i, mx);
            float alpha = __builtin_amdgcn_exp2f(m_i - mnew);
            float sm = 0.f;
            short4v pp[4];
            #pragma unroll
            for (int kg = 0; kg < 4; kg++) {
                float p0 = __builtin_amdgcn_exp2f(s[kg][0] - mnew);
                float p1 = __builtin_amdgcn_exp2f(s[kg][1] - mnew);
                float p2 = __builtin_amdgcn_exp2f(s[kg][2] - mnew);
                float p3 = __builtin_amdgcn_exp2f(s[kg][3] - mnew);
                sm += (p0 + p1) + (p2 + p3);
                union { float f; unsigned u; } c0, c1, c2, c3;
                c0.f = p0; c1.f = p1; c2.f = p2; c3.f = p3;
                union { short4v s4; unsigned u[2]; } pu;
                pu.u[0] = (c0.u >> 16) | (c1.u & 0xFFFF0000u);   // truncated bf16
                pu.u[1] = (c2.u >> 16) | (c3.u & 0xFFFF0000u);
                pp[kg] = pu.s4;
            }
            sm += __shfl_xor(sm, 16);
            sm += __shfl_xor(sm, 32);
            l_i = l_i * alpha + sm;
            m_i = mnew;

            // PV: O^T[d][qrow] += V^T . P^T   (K=16 per key-group)
            #pragma unroll
            for (int dt = 0; dt < 8; dt++) {
                f32x4 oo = o[dt];
                #pragma unroll
                for (int r = 0; r < 4; r++) oo[r] *= alpha;
                #pragma unroll
                for (int kg = 0; kg < 4; kg++) {
                    int un = (kg * 4 + quad) ^ (lo & 14);     // vrow&14 == lo&14
                    short4v vv = *(const short4v*)(Vc + (dt * 16 + lo) * 64 + un * 4);
                    oo = pv_mfma(vv, pp[kg], oo);
                }
                o[dt] = oo;
            }
        }
        __asm__ volatile("" ::: "memory");
        __builtin_amdgcn_s_barrier();
        __asm__ volatile("" ::: "memory");
    }

    // epilogue: O^T C-layout lane(quad,lo): d = dt*16+quad*4+r, qrow = G+lo
    float inv_l = 1.f / l_i;
    size_t base = ((size_t)b * T_SEQ + G + lo) * C_DIM + h * D_HEAD + quad * 4;
    #pragma unroll
    for (int dt = 0; dt < 8; dt++) {
        uint2 u;
        u.x = (unsigned)f2bf(o[dt][0] * inv_l) | ((unsigned)f2bf(o[dt][1] * inv_l) << 16);
        u.y = (unsigned)f2bf(o[dt][2] * inv_l) | ((unsigned)f2bf(o[dt][3] * inv_l) << 16);
        *(uint2*)(attn_out + base + dt * 16) = u;
    }
}

__global__ __launch_bounds__(512, 4) void attn_kernel(const unsigned short* __restrict__ q,
                                                      const unsigned short* __restrict__ k,
                                                      const unsigned short* __restrict__ vt,
                                                      unsigned short* __restrict__ attn_out) {
    __shared__ unsigned short Kb[2 * 64 * 128];   // 32 KB
    __shared__ unsigned short Vb[2 * 128 * 64];   // 32 KB
    const int lane = threadIdx.x & 63;
    const int w = threadIdx.x >> 6;               // 0..7
    const int quad = lane >> 4, lo = lane & 15;
    const int bid = blockIdx.x;                   // 512 blocks = 2/CU
    const int head_lin = bid & 63;                // same head => same XCD (bid%8 const)
    const int pr = bid >> 6;                      // pair index 0..7
    const int b = head_lin >> 4, h = head_lin & 15;
    const unsigned short* qh = q + (size_t)head_lin * T_SEQ * D_HEAD;
    const unsigned short* kh = k + (size_t)head_lin * T_SEQ * D_HEAD;
    const unsigned short* vh = vt + (size_t)head_lin * D_HEAD * T_SEQ;

    attn_tile128(qh, kh, vh, attn_out, pr,      b, h, w, quad, lo, lane, Kb, Vb);  // light
    attn_tile128(qh, kh, vh, attn_out, 15 - pr, b, h, w, quad, lo, lane, Kb, Vb);  // heavy
}

// ---------------- launch -----------------------------------------------------
extern "C" void kernel_launch(void* const* d_in, const int* in_sizes, int n_in,
                              void* d_out, int out_size, void* d_ws, size_t ws_size,
                              hipStream_t stream) {
    const float* x    = (const float*)d_in[0];
    const float* ln_g = (const float*)d_in[1];
    const float* ln_b = (const float*)d_in[2];
    const float* Wq   = (const float*)d_in[3];
    const float* bq   = (const float*)d_in[4];
    const float* Wk   = (const float*)d_in[5];
    const float* bk   = (const float*)d_in[6];
    const float* Wv   = (const float*)d_in[7];
    const float* bv   = (const float*)d_in[8];
    const float* Wo   = (const float*)d_in[9];
    const float* bo   = (const float*)d_in[10];
    float* out = (float*)d_out;

    char* ws = (char*)d_ws;
    const size_t SZ = (size_t)M_ROWS * C_DIM * 2;        // 33,554,432 bytes
    unsigned short* nx  = (unsigned short*)(ws);
    unsigned short* wt  = (unsigned short*)(ws + SZ);    // 4 x 2048 x 2048 bf16
    unsigned short* qb  = (unsigned short*)(ws + 2 * SZ);
    unsigned short* kb  = (unsigned short*)(ws + 3 * SZ);
    unsigned short* vtb = (unsigned short*)(ws + 4 * SZ);
    unsigned short* at  = (unsigned short*)(ws + 5 * SZ);

    static bool lds_inited = false;
    if (!lds_inited) {
        hipFuncSetAttribute((const void*)gemm_qkv,
                            hipFuncAttributeMaxDynamicSharedMemorySize, 65536);
        hipFuncSetAttribute((const void*)gemm_out,
                            hipFuncAttributeMaxDynamicSharedMemorySize, 65536);
        lds_inited = true;
    }

    wcast_kernel<<<dim3(64, 64, 4), dim3(32, 8), 0, stream>>>(Wq, Wk, Wv, Wo, wt);
    ln_kernel<<<M_ROWS, 256, 0, stream>>>(x, ln_g, ln_b, nx);
    gemm_qkv<<<768, 512, 65536, stream>>>(nx, wt, bq, bk, bv, qb, kb, vtb);
    rope_kernel<<<dim3((B_NUM * H_NUM * T_SEQ * 64) / 256, 2), 256, 0, stream>>>(qb, kb);
    attn_kernel<<<512, 512, 0, stream>>>(qb, kb, vtb, at);
    gemm_out<<<256, 512, 65536, stream>>>(at, wt + (size_t)3 * C_DIM * C_DIM, bo, x, out);
}

// Round 5
// 696.585 us; speedup vs baseline: 1.1417x; 1.1417x over previous
//
#include <hip/hip_runtime.h>

typedef short short8 __attribute__((ext_vector_type(8)));
typedef short short4v __attribute__((ext_vector_type(4)));
typedef float f32x4 __attribute__((ext_vector_type(4)));

#define T_SEQ 2048
#define C_DIM 2048
#define H_NUM 16
#define D_HEAD 128
#define B_NUM 4
#define M_ROWS (B_NUM * T_SEQ)   // 8192

__device__ __forceinline__ unsigned short f2bf(float f) {
    union { float f; unsigned u; } v; v.f = f;
    unsigned r = v.u + 0x7FFFu + ((v.u >> 16) & 1u);
    return (unsigned short)(r >> 16);
}
__device__ __forceinline__ float bf2f(unsigned short u) {
    union { unsigned u; float f; } v; v.u = ((unsigned)u) << 16;
    return v.f;
}

// async global->LDS, 16B per lane; lds ptr wave-uniform (HW adds lane*16)
__device__ __forceinline__ void async_ld16(const unsigned short* g, unsigned short* l) {
    __builtin_amdgcn_global_load_lds(
        (const __attribute__((address_space(1))) unsigned int*)g,
        (__attribute__((address_space(3))) unsigned int*)l,
        16, 0, 0);
}

__device__ __forceinline__ f32x4 pv_mfma(short4v v, short4v p, f32x4 c) {
#if __has_builtin(__builtin_amdgcn_mfma_f32_16x16x16bf16_1k)
    return __builtin_amdgcn_mfma_f32_16x16x16bf16_1k(v, p, c, 0, 0, 0);
#else
    short8 vf = {v[0], v[1], v[2], v[3], 0, 0, 0, 0};
    short8 pf = {p[0], p[1], p[2], p[3], 0, 0, 0, 0};
    return __builtin_amdgcn_mfma_f32_16x16x32_bf16(vf, pf, c, 0, 0, 0);
#endif
}

// ============================================================================
// Packed-B weight layout (bf16), produced by wcast_kernel, consumed by GEMMs.
// Element index:
//   idx = (((cb*32 + t)*4 + wn)*8 + f)*512 + lane*8 + e
//   where f = qn*4 + ni*2 + ks,  lane = quad*16 + lo,
//         n = cb*256 + qn*128 + wn*32 + ni*16 + lo,
//         k = t*64 + ks*32 + quad*8 + e.
// Each frag (512 elems = 1KB) is exactly one wave's MFMA B-operand, stored
// lane-major -> the GEMM-side load is 64 lanes x 16B fully contiguous.
// Round-4 lesson: B direct-to-reg from row-major Bt had 4KB-stride/lane ->
// 64 cache lines per load instr -> VMEM choke (371us, MfmaUtil 23%).
// ============================================================================
#define GBK 64
#define GNT (C_DIM / GBK)        // 32 K-tiles
#define PK_FRAG 512
#define PK_WN   (8 * PK_FRAG)    // 4096
#define PK_CBT  (4 * PK_WN)      // 16384 elems per (cb,t)

// wcast: grid (32 t, 8 cb, 4 w), 256 threads. LDS transpose then packed write.
__global__ __launch_bounds__(256) void wcast_kernel(const float* __restrict__ W0,
                                                    const float* __restrict__ W1,
                                                    const float* __restrict__ W2,
                                                    const float* __restrict__ W3,
                                                    unsigned short* __restrict__ wt) {
    __shared__ unsigned short tl[256 * 72];   // tl[n_local*72 + k_local], 36 KB
    const float* W = (blockIdx.z == 0) ? W0 : (blockIdx.z == 1) ? W1 :
                     (blockIdx.z == 2) ? W2 : W3;
    unsigned short* out = wt + (size_t)blockIdx.z * C_DIM * C_DIM;
    const int t = blockIdx.x, cb = blockIdx.y;
    const int tid = threadIdx.x;

    // load: thread owns n_local = tid; reads 64 k values (coalesced across tid)
    const float* src = W + (size_t)(t * 64) * C_DIM + cb * 256 + tid;
    unsigned short* dst = tl + tid * 72;
    #pragma unroll
    for (int c = 0; c < 8; c++) {
        unsigned short v[8];
        #pragma unroll
        for (int e = 0; e < 8; e++) v[e] = f2bf(src[(size_t)(c * 8 + e) * C_DIM]);
        union { short8 s; unsigned short u[8]; } pk;
        #pragma unroll
        for (int e = 0; e < 8; e++) pk.u[e] = v[e];
        *(short8*)(dst + c * 8) = pk.s;
    }
    __syncthreads();

    // write packed: thread handles units u = s*256 + tid
    const int wv = tid >> 6, l = tid & 63;
    const int quad = l >> 4, lo = l & 15;
    const size_t bb = ((size_t)(cb * GNT + t) * 4) * PK_WN;
    #pragma unroll
    for (int s = 0; s < 8; s++) {
        int F = s * 4 + wv;                 // 0..31
        int wn = F >> 3, f = F & 7;
        int qn = f >> 2, ni = (f >> 1) & 1, ks = f & 1;
        int n_local = qn * 128 + wn * 32 + ni * 16 + lo;
        int k_local = ks * 32 + quad * 8;
        short8 v = *(const short8*)(tl + n_local * 72 + k_local);
        *(short8*)(out + bb + (size_t)wn * PK_WN + (size_t)f * PK_FRAG + l * 8) = v;
    }
}

// ---------------- LayerNorm -> bf16 ----------------------------------------
__global__ __launch_bounds__(256) void ln_kernel(const float* __restrict__ x,
                                                 const float* __restrict__ g,
                                                 const float* __restrict__ bta,
                                                 unsigned short* __restrict__ nx) {
    int row = blockIdx.x;
    int tid = threadIdx.x;
    const float* xr = x + (size_t)row * C_DIM;
    float4 v0 = *(const float4*)(xr + tid * 8);
    float4 v1 = *(const float4*)(xr + tid * 8 + 4);
    float s = v0.x + v0.y + v0.z + v0.w + v1.x + v1.y + v1.z + v1.w;
    float q = v0.x * v0.x + v0.y * v0.y + v0.z * v0.z + v0.w * v0.w +
              v1.x * v1.x + v1.y * v1.y + v1.z * v1.z + v1.w * v1.w;
    #pragma unroll
    for (int m = 32; m; m >>= 1) { s += __shfl_xor(s, m); q += __shfl_xor(q, m); }
    __shared__ float red[2][4];
    int wave = tid >> 6, lane = tid & 63;
    if (lane == 0) { red[0][wave] = s; red[1][wave] = q; }
    __syncthreads();
    s = red[0][0] + red[0][1] + red[0][2] + red[0][3];
    q = red[1][0] + red[1][1] + red[1][2] + red[1][3];
    float mu = s * (1.0f / C_DIM);
    float var = q * (1.0f / C_DIM) - mu * mu;
    float rstd = rsqrtf(var + 1e-5f);
    float4 g0 = *(const float4*)(g + tid * 8);
    float4 g1 = *(const float4*)(g + tid * 8 + 4);
    float4 b0 = *(const float4*)(bta + tid * 8);
    float4 b1 = *(const float4*)(bta + tid * 8 + 4);
    unsigned short o[8];
    o[0] = f2bf((v0.x - mu) * rstd * g0.x + b0.x);
    o[1] = f2bf((v0.y - mu) * rstd * g0.y + b0.y);
    o[2] = f2bf((v0.z - mu) * rstd * g0.z + b0.z);
    o[3] = f2bf((v0.w - mu) * rstd * g0.w + b0.w);
    o[4] = f2bf((v1.x - mu) * rstd * g1.x + b1.x);
    o[5] = f2bf((v1.y - mu) * rstd * g1.y + b1.y);
    o[6] = f2bf((v1.z - mu) * rstd * g1.z + b1.z);
    o[7] = f2bf((v1.w - mu) * rstd * g1.w + b1.w);
    uint4 pk;
    pk.x = (unsigned)o[0] | ((unsigned)o[1] << 16);
    pk.y = (unsigned)o[2] | ((unsigned)o[3] << 16);
    pk.z = (unsigned)o[4] | ((unsigned)o[5] << 16);
    pk.w = (unsigned)o[6] | ((unsigned)o[7] << 16);
    *(uint4*)(nx + (size_t)row * C_DIM + tid * 8) = pk;
}

// ============================================================================
// 256x256 / BK=64 / 8-wave GEMM core: A in LDS (dbuf 64KB), B packed->regs.
// Per tile t (A from buf[t&1]; cb0/cb1 loaded at end of tile t-1):
//   RDA(qm0); c1 af*cb0; c2 af*cb1; RDA(qm1);
//   BAR#1;
//   c3 af*cb1; c4 af*cb0;
//   LOADB(t+1) (8 coalesced 1KB/wave loads);
//   STAGE A(t+2) -> buf[t&1] (4 DMA);
//   vmcnt(12); BAR#2.
// vmcnt algebra (in-order): at boundary outstanding = A(t+1)4 + B(t+1)8 +
//   A(t+2)4 = 16; vmcnt(12) retires exactly A(t+1) (the DMA->ds_read hazard
//   the compiler can't track). c1's compiler wait retires only B (long done).
//   Tail (t+2>=GNT): vmcnt(0) drains (A(t+1) must land; closes R4 tail race).
// ============================================================================

#define GFENCE __asm__ volatile("" ::: "memory")
#define GBAR do { GFENCE; __builtin_amdgcn_s_barrier(); GFENCE; } while (0)

__device__ __forceinline__ void mfma16(const short8 af[4][2], const short8 bf[2][2],
                                       f32x4 acc[4][2]) {
    __builtin_amdgcn_s_setprio(1);
    #pragma unroll
    for (int mi = 0; mi < 4; mi++)
        #pragma unroll
        for (int ni = 0; ni < 2; ni++)
            #pragma unroll
            for (int ks = 0; ks < 2; ks++)
                acc[mi][ni] = __builtin_amdgcn_mfma_f32_16x16x32_bf16(af[mi][ks], bf[ni][ks],
                                                                      acc[mi][ni], 0, 0, 0);
    __builtin_amdgcn_s_setprio(0);
}

__device__ __forceinline__ void gemm_core256(const unsigned short* __restrict__ gA,
                                             const unsigned short* __restrict__ gBp,
                                             unsigned short* lds,
                                             f32x4 acc[2][2][4][2]) {
    const int tid = threadIdx.x;
    const int lane = tid & 63, w = tid >> 6;
    const int quad = lane >> 4, lo = lane & 15;
    const int wm = w >> 2;

    // A LDS read base (elements); chunk-XOR swizzle (verified, 0 conflicts)
    const int swz8 = (quad ^ (lo & 7)) * 8;
    const int aoff = (wm * 64 + lo) * 64 + swz8;

    // A staging: per-lane pre-swizzled global offsets + wave-uniform LDS dests
    const int r8 = lane >> 3, c8 = lane & 7;
    const int goff0 = (w * 8 + r8) * C_DIM + ((c8 ^ r8) << 3);
    const int goff1 = (64 + w * 8 + r8) * C_DIM + ((c8 ^ r8) << 3);
    const int ldst0 = (w * 8) * 64;
    const int ldst1 = (64 + w * 8) * 64;

    unsigned short* const L0 = lds;            // 16384 elems (32 KB)
    unsigned short* const L1 = lds + 16384;

    const unsigned short* gA1 = gA + (size_t)128 * C_DIM;

#define STAGE(gbase, lregion) do { \
        async_ld16((gbase) + goff0, (lregion) + ldst0); \
        async_ld16((gbase) + goff1, (lregion) + ldst1); \
    } while (0)

#define RDA(As, qm, dst) do { \
        _Pragma("unroll") \
        for (int mi = 0; mi < 4; mi++) { \
            dst[mi][0] = *(const short8*)((As) + (((qm) * 8192 + mi * 1024 + aoff))); \
            dst[mi][1] = *(const short8*)((As) + (((qm) * 8192 + mi * 1024 + aoff) ^ 32)); \
        } \
    } while (0)

#define LOADB(tt) do { \
        const unsigned short* _b = gBp + (size_t)(tt) * PK_CBT; \
        cb0[0][0] = *(const short8*)(_b); \
        cb0[0][1] = *(const short8*)(_b + 1 * PK_FRAG); \
        cb0[1][0] = *(const short8*)(_b + 2 * PK_FRAG); \
        cb0[1][1] = *(const short8*)(_b + 3 * PK_FRAG); \
        cb1[0][0] = *(const short8*)(_b + 4 * PK_FRAG); \
        cb1[0][1] = *(const short8*)(_b + 5 * PK_FRAG); \
        cb1[1][0] = *(const short8*)(_b + 6 * PK_FRAG); \
        cb1[1][1] = *(const short8*)(_b + 7 * PK_FRAG); \
    } while (0)

    short8 cb0[2][2], cb1[2][2];

    // prologue: B(0) 8 + A(0) 4 + A(1) 4 = 16 outstanding;
    // vmcnt(4) retires B(0)+A(0), keeps A(1) in flight.
    LOADB(0);
    STAGE(gA, L0); STAGE(gA1, L0 + 8192);                 // A(0)
    STAGE(gA + GBK, L1); STAGE(gA1 + GBK, L1 + 8192);     // A(1)
    __builtin_amdgcn_s_waitcnt(0x3F74);                   // vmcnt(4)
    GBAR;

    for (int t = 0; t < GNT; ++t) {
        const unsigned short* As = (t & 1) ? L1 : L0;
        unsigned short* Lc = (t & 1) ? L1 : L0;           // stage target (for t+2)
        short8 af[4][2];

        RDA(As, 0, af);
        mfma16(af, cb0, acc[0][0]);
        mfma16(af, cb1, acc[0][1]);
        RDA(As, 1, af);
        GBAR;                                             // BAR#1

        mfma16(af, cb1, acc[1][1]);
        mfma16(af, cb0, acc[1][0]);
        if (t + 1 < GNT) LOADB(t + 1);                    // 8 coalesced loads
        if (t + 2 < GNT) {                                // 4 DMA ops
            STAGE(gA + (size_t)(t + 2) * GBK, Lc);
            STAGE(gA1 + (size_t)(t + 2) * GBK, Lc + 8192);
        }
        if (t + 2 < GNT) __builtin_amdgcn_s_waitcnt(0x3F7C);  // vmcnt(12)
        else             __builtin_amdgcn_s_waitcnt(0x3F70);  // tail: drain
        GBAR;                                             // BAR#2
    }
#undef STAGE
#undef RDA
#undef LOADB
}

// ---------------- fused QKV GEMM (N = 6144) ---------------------------------
__global__ __launch_bounds__(512, 2) void gemm_qkv(const unsigned short* __restrict__ A,
                                                   const unsigned short* __restrict__ Bp,
                                                   const float* __restrict__ bq,
                                                   const float* __restrict__ bk,
                                                   const float* __restrict__ bv,
                                                   unsigned short* __restrict__ qb,
                                                   unsigned short* __restrict__ kb,
                                                   unsigned short* __restrict__ vtb) {
    extern __shared__ unsigned short ldsbuf[];
    f32x4 acc[2][2][4][2] = {};
    const int bid = blockIdx.x;                   // 768 blocks, 768%8==0
    const int b2 = (bid & 7) * 96 + (bid >> 3);   // bijective XCD swizzle
    const int rowBase = (b2 / 24) * 256;
    const int colBase = (b2 % 24) * 256;
    const int cbg = b2 % 24;                      // global 256-col block
    const int wslot = cbg >> 3, cbw = cbg & 7;
    const int lane = threadIdx.x & 63, w = threadIdx.x >> 6;
    const int wn = w & 3;
    const unsigned short* gBp = Bp + (size_t)wslot * C_DIM * C_DIM
                                   + (size_t)cbw * GNT * PK_CBT
                                   + (size_t)wn * PK_WN + lane * 8;
    gemm_core256(A + (size_t)rowBase * C_DIM, gBp, ldsbuf, acc);

    const int quad = lane >> 4, lo = lane & 15;
    const int wm = w >> 2;
    const int which = wslot;
    const float* bias = (which == 0) ? bq : (which == 1) ? bk : bv;
    #pragma unroll
    for (int qm = 0; qm < 2; qm++)
        #pragma unroll
        for (int qn = 0; qn < 2; qn++)
            #pragma unroll
            for (int mi = 0; mi < 4; mi++)
                #pragma unroll
                for (int ni = 0; ni < 2; ni++) {
                    int n = colBase + qn * 128 + wn * 32 + ni * 16 + lo;
                    int c = n & (C_DIM - 1), h = c >> 7, d = c & 127;
                    float bsv = bias[c];
                    #pragma unroll
                    for (int r = 0; r < 4; r++) {
                        int m = rowBase + qm * 128 + wm * 64 + mi * 16 + quad * 4 + r;
                        int bb = m >> 11, tt = m & (T_SEQ - 1);
                        unsigned short u = f2bf(acc[qm][qn][mi][ni][r] + bsv);
                        if (which == 2)
                            vtb[(size_t)((bb * H_NUM + h) * D_HEAD + d) * T_SEQ + tt] = u;
                        else if (which == 1)
                            kb[(size_t)((bb * H_NUM + h) * T_SEQ + tt) * D_HEAD + d] = u;
                        else
                            qb[(size_t)((bb * H_NUM + h) * T_SEQ + tt) * D_HEAD + d] = u;
                    }
                }
}

// ---------------- output GEMM + bias + residual -----------------------------
__global__ __launch_bounds__(512, 2) void gemm_out(const unsigned short* __restrict__ A,
                                                   const unsigned short* __restrict__ Bp,
                                                   const float* __restrict__ bo,
                                                   const float* __restrict__ x,
                                                   float* __restrict__ out) {
    extern __shared__ unsigned short ldsbuf[];
    f32x4 acc[2][2][4][2] = {};
    const int bid = blockIdx.x;                   // 256 blocks
    const int b2 = (bid & 7) * 32 + (bid >> 3);
    const int rowBase = (b2 / 8) * 256;
    const int colBase = (b2 % 8) * 256;
    const int cbw = b2 % 8;
    const int lane = threadIdx.x & 63, w = threadIdx.x >> 6;
    const int wn = w & 3;
    const unsigned short* gBp = Bp + (size_t)cbw * GNT * PK_CBT
                                   + (size_t)wn * PK_WN + lane * 8;
    gemm_core256(A + (size_t)rowBase * C_DIM, gBp, ldsbuf, acc);

    const int quad = lane >> 4, lo = lane & 15;
    const int wm = w >> 2;
    #pragma unroll
    for (int qm = 0; qm < 2; qm++)
        #pragma unroll
        for (int qn = 0; qn < 2; qn++)
            #pragma unroll
            for (int mi = 0; mi < 4; mi++)
                #pragma unroll
                for (int ni = 0; ni < 2; ni++) {
                    int n = colBase + qn * 128 + wn * 32 + ni * 16 + lo;
                    float bsv = bo[n];
                    #pragma unroll
                    for (int r = 0; r < 4; r++) {
                        int m = rowBase + qm * 128 + wm * 64 + mi * 16 + quad * 4 + r;
                        size_t idx = (size_t)m * C_DIM + n;
                        out[idx] = x[idx] + acc[qm][qn][mi][ni][r] + bsv;
                    }
                }
}

// ---------------- RoPE (in-place, bf16) -------------------------------------
__global__ __launch_bounds__(256) void rope_kernel(unsigned short* __restrict__ qb,
                                                   unsigned short* __restrict__ kb) {
    const bool isk = (blockIdx.y != 0);
    unsigned short* p = isk ? kb : qb;
    const float osc = isk ? 1.0f : 0.12751736f;    // log2(e)/sqrt(128)
    int pidx = blockIdx.x * 256 + threadIdx.x;     // 0 .. B*H*T*64-1
    int dd = pidx & 63;
    int bht = pidx >> 6;
    int t = bht & (T_SEQ - 1);
    unsigned short* base = p + (size_t)bht * D_HEAD;
    float x0 = bf2f(base[dd]);
    float x1 = bf2f(base[dd + 64]);
    float inv = exp2f((float)dd * (-13.287712379549449f / 64.0f));  // 10000^(-dd/64)
    float ang = (float)t * inv;
    float sn = __sinf(ang), cs = __cosf(ang);
    base[dd]      = f2bf((x0 * cs - x1 * sn) * osc);
    base[dd + 64] = f2bf((x1 * cs + x0 * sn) * osc);
}

// ---------------- causal flash attention (v4, unchanged) ---------------------
__device__ __forceinline__ void attn_stage(const unsigned short* __restrict__ kh,
                                           const unsigned short* __restrict__ vh,
                                           int kt, unsigned short* Kd, unsigned short* Vd,
                                           int w, int lane) {
    const int l4 = lane >> 4, c16 = lane & 15;
    const int l8 = lane >> 3, c8 = lane & 7;
    #pragma unroll
    for (int j = 0; j < 2; j++) {
        int R = w * 8 + j * 4;                     // K rows R..R+3
        int row = R + l4;
        int cl = c16 ^ (row & 15);                 // LDS slot (row,cs) holds chunk cs^row15
        async_ld16(kh + (size_t)(kt * 64 + row) * D_HEAD + cl * 8, Kd + R * D_HEAD);
    }
    #pragma unroll
    for (int j = 0; j < 2; j++) {
        int o8 = w * 2 + j;                        // V 8-row chunk 0..15
        int row = o8 * 8 + l8;
        int gu = (2 * c8) ^ (row & 14);            // 8B-unit swizzle, even mask keeps pairs
        async_ld16(vh + (size_t)row * T_SEQ + kt * 64 + gu * 4, Vd + o8 * 512);
    }
}

__device__ __forceinline__ void attn_tile128(const unsigned short* __restrict__ qh,
                                             const unsigned short* __restrict__ kh,
                                             const unsigned short* __restrict__ vh,
                                             unsigned short* __restrict__ attn_out,
                                             int tile, int b, int h, int w, int quad,
                                             int lo, int lane,
                                             unsigned short* Kb, unsigned short* Vb) {
    const int G = tile * 128 + 16 * w;           // this wave's 16 q-rows
    const int a = (G + 15) >> 6;                 // last needed k-tile
    const int nkt = 2 * tile + 2;
    const int tq = G + lo;

    short8 qf[4];
    #pragma unroll
    for (int ks = 0; ks < 4; ks++)
        qf[ks] = *(const short8*)(qh + (size_t)(G + lo) * D_HEAD + ks * 32 + quad * 8);

    float m_i = -1e30f, l_i = 0.f;
    f32x4 o[8];
    #pragma unroll
    for (int dt = 0; dt < 8; dt++) o[dt] = (f32x4){0.f, 0.f, 0.f, 0.f};

    attn_stage(kh, vh, 0, Kb, Vb, w, lane);
    for (int kt = 0; kt < nkt; kt++) {
        const int cur = kt & 1;
        if (kt + 1 < nkt) {
            attn_stage(kh, vh, kt + 1, Kb + (cur ^ 1) * 8192, Vb + (cur ^ 1) * 8192, w, lane);
            __builtin_amdgcn_s_waitcnt(0x3F74);   // vmcnt(4): this tile's 4 loads done
        } else {
            __builtin_amdgcn_s_waitcnt(0x3F70);   // vmcnt(0)
        }
        __asm__ volatile("" ::: "memory");
        __builtin_amdgcn_s_barrier();
        __asm__ volatile("" ::: "memory");

        if (kt <= a) {                            // wave-uniform
            const unsigned short* Kc = Kb + cur * 8192;
            const unsigned short* Vc = Vb + cur * 8192;
            // QK: S^T[key][qrow] = K . Q^T
            f32x4 s[4];
            #pragma unroll
            for (int kg = 0; kg < 4; kg++) s[kg] = (f32x4){0.f, 0.f, 0.f, 0.f};
            #pragma unroll
            for (int kg = 0; kg < 4; kg++)
                #pragma unroll
                for (int ks = 0; ks < 4; ks++) {
                    int ch = (ks * 4 + quad) ^ lo;            // row&15 == lo
                    short8 kf = *(const short8*)(Kc + (kg * 16 + lo) * D_HEAD + ch * 8);
                    s[kg] = __builtin_amdgcn_mfma_f32_16x16x32_bf16(kf, qf[ks], s[kg], 0, 0, 0);
                }

            // online softmax (exp2 domain; scale folded into Q)
            const bool msk = (kt == a);
            float mx = -1e30f;
            #pragma unroll
            for (int kg = 0; kg < 4; kg++)
                #pragma unroll
                for (int r = 0; r < 4; r++) {
                    if (msk) {
                        int key = kt * 64 + kg * 16 + quad * 4 + r;
                        if (key > tq) s[kg][r] = -1e30f;
                    }
                    mx = fmaxf(mx, s[kg][r]);
                }
            mx = fmaxf(mx, __shfl_xor(mx, 16));
            mx = fmaxf(mx, __shfl_xor(mx, 32));
            float mnew = fmaxf(m_i, mx);
            float alpha = __builtin_amdgcn_exp2f(m_i - mnew);
            float sm = 0.f;
            short4v pp[4];
            #pragma unroll
            for (int kg = 0; kg < 4; kg++) {
                float p0 = __builtin_amdgcn_exp2f(s[kg][0] - mnew);
                float p1 = __builtin_amdgcn_exp2f(s[kg][1] - mnew);
                float p2 = __builtin_amdgcn_exp2f(s[kg][2] - mnew);
                float p3 = __builtin_amdgcn_exp2f(s[kg][3] - mnew);
                sm += (p0 + p1) + (p2 + p3);
                union { float f; unsigned u; } c0, c1, c2, c3;
                c0.f = p0; c1.f = p1; c2.f = p2; c3.f = p3;
                union { short4v s4; unsigned u[2]; } pu;
                pu.u[0] = (c0.u >> 16) | (c1.u & 0xFFFF0000u);   // truncated bf16
                pu.u[1] = (c2.u >> 16) | (c3.u & 0xFFFF0000u);
                pp[kg] = pu.s4;
            }
            sm += __shfl_xor(sm, 16);
            sm += __shfl_xor(sm, 32);
            l_i = l_i * alpha + sm;
            m_i = mnew;

            // PV: O^T[d][qrow] += V^T . P^T   (K=16 per key-group)
            #pragma unroll
            for (int dt = 0; dt < 8; dt++) {
                f32x4 oo = o[dt];
                #pragma unroll
                for (int r = 0; r < 4; r++) oo[r] *= alpha;
                #pragma unroll
                for (int kg = 0; kg < 4; kg++) {
                    int un = (kg * 4 + quad) ^ (lo & 14);     // vrow&14 == lo&14
                    short4v vv = *(const short4v*)(Vc + (dt * 16 + lo) * 64 + un * 4);
                    oo = pv_mfma(vv, pp[kg], oo);
                }
                o[dt] = oo;
            }
        }
        __asm__ volatile("" ::: "memory");
        __builtin_amdgcn_s_barrier();
        __asm__ volatile("" ::: "memory");
    }

    // epilogue: O^T C-layout lane(quad,lo): d = dt*16+quad*4+r, qrow = G+lo
    float inv_l = 1.f / l_i;
    size_t base = ((size_t)b * T_SEQ + G + lo) * C_DIM + h * D_HEAD + quad * 4;
    #pragma unroll
    for (int dt = 0; dt < 8; dt++) {
        uint2 u;
        u.x = (unsigned)f2bf(o[dt][0] * inv_l) | ((unsigned)f2bf(o[dt][1] * inv_l) << 16);
        u.y = (unsigned)f2bf(o[dt][2] * inv_l) | ((unsigned)f2bf(o[dt][3] * inv_l) << 16);
        *(uint2*)(attn_out + base + dt * 16) = u;
    }
}

__global__ __launch_bounds__(512, 4) void attn_kernel(const unsigned short* __restrict__ q,
                                                      const unsigned short* __restrict__ k,
                                                      const unsigned short* __restrict__ vt,
                                                      unsigned short* __restrict__ attn_out) {
    __shared__ unsigned short Kb[2 * 64 * 128];   // 32 KB
    __shared__ unsigned short Vb[2 * 128 * 64];   // 32 KB
    const int lane = threadIdx.x & 63;
    const int w = threadIdx.x >> 6;               // 0..7
    const int quad = lane >> 4, lo = lane & 15;
    const int bid = blockIdx.x;                   // 512 blocks = 2/CU
    const int head_lin = bid & 63;                // same head => same XCD (bid%8 const)
    const int pr = bid >> 6;                      // pair index 0..7
    const int b = head_lin >> 4, h = head_lin & 15;
    const unsigned short* qh = q + (size_t)head_lin * T_SEQ * D_HEAD;
    const unsigned short* kh = k + (size_t)head_lin * T_SEQ * D_HEAD;
    const unsigned short* vh = vt + (size_t)head_lin * D_HEAD * T_SEQ;

    attn_tile128(qh, kh, vh, attn_out, pr,      b, h, w, quad, lo, lane, Kb, Vb);  // light
    attn_tile128(qh, kh, vh, attn_out, 15 - pr, b, h, w, quad, lo, lane, Kb, Vb);  // heavy
}

// ---------------- launch -----------------------------------------------------
extern "C" void kernel_launch(void* const* d_in, const int* in_sizes, int n_in,
                              void* d_out, int out_size, void* d_ws, size_t ws_size,
                              hipStream_t stream) {
    const float* x    = (const float*)d_in[0];
    const float* ln_g = (const float*)d_in[1];
    const float* ln_b = (const float*)d_in[2];
    const float* Wq   = (const float*)d_in[3];
    const float* bq   = (const float*)d_in[4];
    const float* Wk   = (const float*)d_in[5];
    const float* bk   = (const float*)d_in[6];
    const float* Wv   = (const float*)d_in[7];
    const float* bv   = (const float*)d_in[8];
    const float* Wo   = (const float*)d_in[9];
    const float* bo   = (const float*)d_in[10];
    float* out = (float*)d_out;

    char* ws = (char*)d_ws;
    const size_t SZ = (size_t)M_ROWS * C_DIM * 2;        // 33,554,432 bytes
    unsigned short* nx  = (unsigned short*)(ws);
    unsigned short* wt  = (unsigned short*)(ws + SZ);    // 4 x 2048 x 2048 bf16 (packed)
    unsigned short* qb  = (unsigned short*)(ws + 2 * SZ);
    unsigned short* kb  = (unsigned short*)(ws + 3 * SZ);
    unsigned short* vtb = (unsigned short*)(ws + 4 * SZ);
    unsigned short* at  = (unsigned short*)(ws + 5 * SZ);

    static bool lds_inited = false;
    if (!lds_inited) {
        hipFuncSetAttribute((const void*)gemm_qkv,
                            hipFuncAttributeMaxDynamicSharedMemorySize, 65536);
        hipFuncSetAttribute((const void*)gemm_out,
                            hipFuncAttributeMaxDynamicSharedMemorySize, 65536);
        lds_inited = true;
    }

    wcast_kernel<<<dim3(32, 8, 4), 256, 0, stream>>>(Wq, Wk, Wv, Wo, wt);
    ln_kernel<<<M_ROWS, 256, 0, stream>>>(x, ln_g, ln_b, nx);
    gemm_qkv<<<768, 512, 65536, stream>>>(nx, wt, bq, bk, bv, qb, kb, vtb);
    rope_kernel<<<dim3((B_NUM * H_NUM * T_SEQ * 64) / 256, 2), 256, 0, stream>>>(qb, kb);
    attn_kernel<<<512, 512, 0, stream>>>(qb, kb, vtb, at);
    gemm_out<<<256, 512, 65536, stream>>>(at, wt + (size_t)3 * C_DIM * C_DIM, bo, x, out);
}

// Round 7
// 621.978 us; speedup vs baseline: 1.2787x; 1.1200x over previous
//
#include <hip/hip_runtime.h>

typedef short short8 __attribute__((ext_vector_type(8)));
typedef short short4v __attribute__((ext_vector_type(4)));
typedef float f32x4 __attribute__((ext_vector_type(4)));

#define T_SEQ 2048
#define C_DIM 2048
#define H_NUM 16
#define D_HEAD 128
#define B_NUM 4
#define M_ROWS (B_NUM * T_SEQ)   // 8192

__device__ __forceinline__ unsigned short f2bf(float f) {
    union { float f; unsigned u; } v; v.f = f;
    unsigned r = v.u + 0x7FFFu + ((v.u >> 16) & 1u);
    return (unsigned short)(r >> 16);
}
__device__ __forceinline__ float bf2f(unsigned short u) {
    union { unsigned u; float f; } v; v.u = ((unsigned)u) << 16;
    return v.f;
}

// async global->LDS, 16B per lane; lds ptr wave-uniform (HW adds lane*16)
__device__ __forceinline__ void async_ld16(const unsigned short* g, unsigned short* l) {
    __builtin_amdgcn_global_load_lds(
        (const __attribute__((address_space(1))) unsigned int*)g,
        (__attribute__((address_space(3))) unsigned int*)l,
        16, 0, 0);
}

__device__ __forceinline__ f32x4 pv_mfma(short4v v, short4v p, f32x4 c) {
#if __has_builtin(__builtin_amdgcn_mfma_f32_16x16x16bf16_1k)
    return __builtin_amdgcn_mfma_f32_16x16x16bf16_1k(v, p, c, 0, 0, 0);
#else
    short8 vf = {v[0], v[1], v[2], v[3], 0, 0, 0, 0};
    short8 pf = {p[0], p[1], p[2], p[3], 0, 0, 0, 0};
    return __builtin_amdgcn_mfma_f32_16x16x32_bf16(vf, pf, c, 0, 0, 0);
#endif
}

// ---------------- weight cast + transpose: wt[w][n][k] = W_w[k][n] (bf16) ----
__global__ __launch_bounds__(256) void wcast_kernel(const float* __restrict__ W0,
                                                    const float* __restrict__ W1,
                                                    const float* __restrict__ W2,
                                                    const float* __restrict__ W3,
                                                    unsigned short* __restrict__ wt) {
    __shared__ float tile[32][33];
    const float* W = (blockIdx.z == 0) ? W0 : (blockIdx.z == 1) ? W1 : (blockIdx.z == 2) ? W2 : W3;
    unsigned short* out = wt + (size_t)blockIdx.z * C_DIM * C_DIM;
    int tx = threadIdx.x, ty = threadIdx.y;      // block (32, 8)
    int n0 = blockIdx.x * 32, k0 = blockIdx.y * 32;
    #pragma unroll
    for (int j = 0; j < 32; j += 8)
        tile[ty + j][tx] = W[(size_t)(k0 + ty + j) * C_DIM + n0 + tx];
    __syncthreads();
    #pragma unroll
    for (int j = 0; j < 32; j += 8)
        out[(size_t)(n0 + ty + j) * C_DIM + k0 + tx] = f2bf(tile[tx][ty + j]);
}

// ---------------- LayerNorm -> bf16 ----------------------------------------
__global__ __launch_bounds__(256) void ln_kernel(const float* __restrict__ x,
                                                 const float* __restrict__ g,
                                                 const float* __restrict__ bta,
                                                 unsigned short* __restrict__ nx) {
    int row = blockIdx.x;
    int tid = threadIdx.x;
    const float* xr = x + (size_t)row * C_DIM;
    float4 v0 = *(const float4*)(xr + tid * 8);
    float4 v1 = *(const float4*)(xr + tid * 8 + 4);
    float s = v0.x + v0.y + v0.z + v0.w + v1.x + v1.y + v1.z + v1.w;
    float q = v0.x * v0.x + v0.y * v0.y + v0.z * v0.z + v0.w * v0.w +
              v1.x * v1.x + v1.y * v1.y + v1.z * v1.z + v1.w * v1.w;
    #pragma unroll
    for (int m = 32; m; m >>= 1) { s += __shfl_xor(s, m); q += __shfl_xor(q, m); }
    __shared__ float red[2][4];
    int wave = tid >> 6, lane = tid & 63;
    if (lane == 0) { red[0][wave] = s; red[1][wave] = q; }
    __syncthreads();
    s = red[0][0] + red[0][1] + red[0][2] + red[0][3];
    q = red[1][0] + red[1][1] + red[1][2] + red[1][3];
    float mu = s * (1.0f / C_DIM);
    float var = q * (1.0f / C_DIM) - mu * mu;
    float rstd = rsqrtf(var + 1e-5f);
    float4 g0 = *(const float4*)(g + tid * 8);
    float4 g1 = *(const float4*)(g + tid * 8 + 4);
    float4 b0 = *(const float4*)(bta + tid * 8);
    float4 b1 = *(const float4*)(bta + tid * 8 + 4);
    unsigned short o[8];
    o[0] = f2bf((v0.x - mu) * rstd * g0.x + b0.x);
    o[1] = f2bf((v0.y - mu) * rstd * g0.y + b0.y);
    o[2] = f2bf((v0.z - mu) * rstd * g0.z + b0.z);
    o[3] = f2bf((v0.w - mu) * rstd * g0.w + b0.w);
    o[4] = f2bf((v1.x - mu) * rstd * g1.x + b1.x);
    o[5] = f2bf((v1.y - mu) * rstd * g1.y + b1.y);
    o[6] = f2bf((v1.z - mu) * rstd * g1.z + b1.z);
    o[7] = f2bf((v1.w - mu) * rstd * g1.w + b1.w);
    uint4 pk;
    pk.x = (unsigned)o[0] | ((unsigned)o[1] << 16);
    pk.y = (unsigned)o[2] | ((unsigned)o[3] << 16);
    pk.z = (unsigned)o[4] | ((unsigned)o[5] << 16);
    pk.w = (unsigned)o[6] | ((unsigned)o[7] << 16);
    *(uint4*)(nx + (size_t)row * C_DIM + tid * 8) = pk;
}

// ============================================================================
// 256x256 / BK=64 / 8-wave GEMM core, TWO barriers per K-tile.
// (R3-benched structure, verified best: gemm_qkv 235.8us, 0 bank conflicts.)
//
// LDS (dynamic, 128 KiB): 2 buffers x { A[256][64], B[256][64] } bf16.
//   Regions (elements): Ah0=0, Ah1=8192, Bh0=16384, Bh1=24576.
//   XOR chunk swizzle: 16B-chunk c of row r at slot c^(r&7); global source
//   pre-swizzled (global_load_lds dest is linear).
// Per tile t (reads from buf[t&1]):
//   rd af0,bf0,bf1 (16 ds_read); stage (t+1).Ah1/Bh1 -> buf[t+1];
//   MFMA (0,0),(0,1); rd af1 (Ah1 - disjoint from staged regions);
//   BAR#1; stage (t+2).Ah0/Bh0 -> buf[t];
//   MFMA (1,1),(1,0); vmcnt(4) (or 0 at tail); BAR#2.
// Hazard notes (R6 lesson: vmcnt is PER-WAVE; any LDS read of a region
// DMA-written by another wave must be preceded by wait->barrier in all
// waves): every read here happens after the boundary barrier that postdates
// all waves' vmcnt(4) -> tile t fully resident. Stage-vs-read WAR: each
// staged region's last CU-wide read completion precedes the issuing point
// by >=1 barrier (see R3 analysis).
// ============================================================================

#define GBK 64
#define GNT (C_DIM / GBK)        // 32 K-tiles

#define GFENCE __asm__ volatile("" ::: "memory")
#define GBAR do { GFENCE; __builtin_amdgcn_s_barrier(); GFENCE; } while (0)

__device__ __forceinline__ void mfma16(const short8 af[4][2], const short8 bf[2][2],
                                       f32x4 acc[4][2]) {
    __builtin_amdgcn_s_setprio(1);
    #pragma unroll
    for (int mi = 0; mi < 4; mi++)
        #pragma unroll
        for (int ni = 0; ni < 2; ni++)
            #pragma unroll
            for (int ks = 0; ks < 2; ks++)
                acc[mi][ni] = __builtin_amdgcn_mfma_f32_16x16x32_bf16(af[mi][ks], bf[ni][ks],
                                                                      acc[mi][ni], 0, 0, 0);
    __builtin_amdgcn_s_setprio(0);
}

__device__ __forceinline__ void gemm_core256(const unsigned short* __restrict__ A,
                                             const unsigned short* __restrict__ Bt,
                                             unsigned short* lds,
                                             int rowBase, int colBase,
                                             f32x4 acc[2][2][4][2]) {
    const int tid = threadIdx.x;
    const int lane = tid & 63, w = tid >> 6;
    const int quad = lane >> 4, lo = lane & 15;
    const int wm = w >> 2, wn = w & 3;

    // precomputed LDS read bases (elements)
    const int swz8 = (quad ^ (lo & 7)) * 8;
    const int aoff = (wm * 64 + lo) * 64 + swz8;
    const int boff = (wn * 32 + lo) * 64 + swz8;

    // precomputed per-lane global stage offsets (elements) + LDS dest offsets
    const int r8 = lane >> 3, c8 = lane & 7;
    const int goff0 = (w * 8 + r8) * C_DIM + ((c8 ^ r8) << 3);
    const int goff1 = (64 + w * 8 + r8) * C_DIM + ((c8 ^ r8) << 3);
    const int ldst0 = (w * 8) * 64;
    const int ldst1 = (64 + w * 8) * 64;

    unsigned short* const L0 = lds;
    unsigned short* const L1 = lds + 32768;

    const unsigned short* gA0 = A + (size_t)rowBase * C_DIM;
    const unsigned short* gA1 = gA0 + (size_t)128 * C_DIM;
    const unsigned short* gB0 = Bt + (size_t)colBase * C_DIM;
    const unsigned short* gB1 = gB0 + (size_t)128 * C_DIM;

#define STAGE(gbase, lregion) do { \
        async_ld16((gbase) + goff0, (lregion) + ldst0); \
        async_ld16((gbase) + goff1, (lregion) + ldst1); \
    } while (0)

#define RDA(As, qm, dst) do { \
        _Pragma("unroll") \
        for (int mi = 0; mi < 4; mi++) { \
            dst[mi][0] = *(const short8*)((As) + (((qm) * 8192 + mi * 1024 + aoff))); \
            dst[mi][1] = *(const short8*)((As) + (((qm) * 8192 + mi * 1024 + aoff) ^ 32)); \
        } \
    } while (0)

#define RDB(Bs, qn, dst) do { \
        _Pragma("unroll") \
        for (int ni = 0; ni < 2; ni++) { \
            dst[ni][0] = *(const short8*)((Bs) + (((qn) * 8192 + ni * 1024 + boff))); \
            dst[ni][1] = *(const short8*)((Bs) + (((qn) * 8192 + ni * 1024 + boff) ^ 32)); \
        } \
    } while (0)

    // prologue: t0 all 4 halves + t1.{Ah0,Bh0}; vmcnt(4) -> t0 resident,
    // t1's two halves stay in flight (steady-state queue shape).
    STAGE(gA0,      L0);             // (0).Ah0
    STAGE(gB0,      L0 + 16384);     // (0).Bh0
    STAGE(gA1,      L0 + 8192);      // (0).Ah1
    STAGE(gB1,      L0 + 24576);     // (0).Bh1
    STAGE(gA0 + 64, L1);             // (1).Ah0
    STAGE(gB0 + 64, L1 + 16384);     // (1).Bh0
    __builtin_amdgcn_s_waitcnt(0x3F74);            // vmcnt(4)
    GBAR;

    for (int t = 0; t < GNT; ++t) {
        const unsigned short* As = (t & 1) ? L1 : L0;
        const unsigned short* Bs = As + 16384;
        unsigned short* Ln = (t & 1) ? L0 : L1;    // buf[(t+1)&1]
        unsigned short* Lc = (t & 1) ? L1 : L0;    // buf[t&1]
        short8 af[4][2], bf0[2][2], bf1[2][2];

        // ---- first half: all reads for quadrants (0,*), stage next-buf ----
        RDA(As, 0, af);
        RDB(Bs, 0, bf0);
        RDB(Bs, 1, bf1);
        if (t + 1 < GNT) {
            STAGE(gA1 + (t + 1) * GBK, Ln + 8192);   // (t+1).Ah1
            STAGE(gB1 + (t + 1) * GBK, Ln + 24576);  // (t+1).Bh1
        }
        mfma16(af, bf0, acc[0][0]);
        mfma16(af, bf1, acc[0][1]);
        RDA(As, 1, af);                              // Ah1: disjoint from staged regions
        GBAR;                                        // BAR#1

        // ---- second half: stage cur-buf (t+2), finish quadrants (1,*) ----
        if (t + 2 < GNT) {
            STAGE(gA0 + (t + 2) * GBK, Lc);          // (t+2).Ah0
            STAGE(gB0 + (t + 2) * GBK, Lc + 16384);  // (t+2).Bh0
        }
        mfma16(af, bf1, acc[1][1]);
        mfma16(af, bf0, acc[1][0]);

        // ---- boundary: tile t+1 resident; keep (t+2) halves in flight ----
        if (t + 2 < GNT) __builtin_amdgcn_s_waitcnt(0x3F74);   // vmcnt(4)
        else             __builtin_amdgcn_s_waitcnt(0x3F70);   // vmcnt(0)
        GBAR;
    }
#undef STAGE
#undef RDA
#undef RDB
}

// ---------------- fused QKV GEMM (N = 6144) ---------------------------------
__global__ __launch_bounds__(512, 2) void gemm_qkv(const unsigned short* __restrict__ A,
                                                   const unsigned short* __restrict__ Bt,
                                                   const float* __restrict__ bq,
                                                   const float* __restrict__ bk,
                                                   const float* __restrict__ bv,
                                                   unsigned short* __restrict__ qb,
                                                   unsigned short* __restrict__ kb,
                                                   unsigned short* __restrict__ vtb) {
    extern __shared__ unsigned short ldsbuf[];
    f32x4 acc[2][2][4][2] = {};
    const int bid = blockIdx.x;                   // 768 blocks, 768%8==0
    const int b2 = (bid & 7) * 96 + (bid >> 3);   // bijective XCD swizzle
    const int rowBase = (b2 / 24) * 256;
    const int colBase = (b2 % 24) * 256;
    gemm_core256(A, Bt, ldsbuf, rowBase, colBase, acc);

    const int lane = threadIdx.x & 63, w = threadIdx.x >> 6;
    const int quad = lane >> 4, lo = lane & 15;
    const int wm = w >> 2, wn = w & 3;
    const int which = colBase >> 11;              // 256-tiles never straddle 2048
    const float* bias = (which == 0) ? bq : (which == 1) ? bk : bv;
    #pragma unroll
    for (int qm = 0; qm < 2; qm++)
        #pragma unroll
        for (int qn = 0; qn < 2; qn++)
            #pragma unroll
            for (int mi = 0; mi < 4; mi++)
                #pragma unroll
                for (int ni = 0; ni < 2; ni++) {
                    int n = colBase + qn * 128 + wn * 32 + ni * 16 + lo;
                    int c = n & (C_DIM - 1), h = c >> 7, d = c & 127;
                    float bsv = bias[c];
                    #pragma unroll
                    for (int r = 0; r < 4; r++) {
                        int m = rowBase + qm * 128 + wm * 64 + mi * 16 + quad * 4 + r;
                        int bb = m >> 11, tt = m & (T_SEQ - 1);
                        unsigned short u = f2bf(acc[qm][qn][mi][ni][r] + bsv);
                        if (which == 2)
                            vtb[(size_t)((bb * H_NUM + h) * D_HEAD + d) * T_SEQ + tt] = u;
                        else if (which == 1)
                            kb[(size_t)((bb * H_NUM + h) * T_SEQ + tt) * D_HEAD + d] = u;
                        else
                            qb[(size_t)((bb * H_NUM + h) * T_SEQ + tt) * D_HEAD + d] = u;
                    }
                }
}

// ---------------- output GEMM + bias + residual -----------------------------
__global__ __launch_bounds__(512, 2) void gemm_out(const unsigned short* __restrict__ A,
                                                   const unsigned short* __restrict__ Bt,
                                                   const float* __restrict__ bo,
                                                   const float* __restrict__ x,
                                                   float* __restrict__ out) {
    extern __shared__ unsigned short ldsbuf[];
    f32x4 acc[2][2][4][2] = {};
    const int bid = blockIdx.x;                   // 256 blocks
    const int b2 = (bid & 7) * 32 + (bid >> 3);
    const int rowBase = (b2 / 8) * 256;
    const int colBase = (b2 % 8) * 256;
    gemm_core256(A, Bt, ldsbuf, rowBase, colBase, acc);

    const int lane = threadIdx.x & 63, w = threadIdx.x >> 6;
    const int quad = lane >> 4, lo = lane & 15;
    const int wm = w >> 2, wn = w & 3;
    #pragma unroll
    for (int qm = 0; qm < 2; qm++)
        #pragma unroll
        for (int qn = 0; qn < 2; qn++)
            #pragma unroll
            for (int mi = 0; mi < 4; mi++)
                #pragma unroll
                for (int ni = 0; ni < 2; ni++) {
                    int n = colBase + qn * 128 + wn * 32 + ni * 16 + lo;
                    float bsv = bo[n];
                    #pragma unroll
                    for (int r = 0; r < 4; r++) {
                        int m = rowBase + qm * 128 + wm * 64 + mi * 16 + quad * 4 + r;
                        size_t idx = (size_t)m * C_DIM + n;
                        out[idx] = x[idx] + acc[qm][qn][mi][ni][r] + bsv;
                    }
                }
}

// ---------------- RoPE (in-place, bf16) -------------------------------------
__global__ __launch_bounds__(256) void rope_kernel(unsigned short* __restrict__ qb,
                                                   unsigned short* __restrict__ kb) {
    const bool isk = (blockIdx.y != 0);
    unsigned short* p = isk ? kb : qb;
    const float osc = isk ? 1.0f : 0.12751736f;    // log2(e)/sqrt(128)
    int pidx = blockIdx.x * 256 + threadIdx.x;     // 0 .. B*H*T*64-1
    int dd = pidx & 63;
    int bht = pidx >> 6;
    int t = bht & (T_SEQ - 1);
    unsigned short* base = p + (size_t)bht * D_HEAD;
    float x0 = bf2f(base[dd]);
    float x1 = bf2f(base[dd + 64]);
    float inv = exp2f((float)dd * (-13.287712379549449f / 64.0f));  // 10000^(-dd/64)
    float ang = (float)t * inv;
    float sn = __sinf(ang), cs = __cosf(ang);
    base[dd]      = f2bf((x0 * cs - x1 * sn) * osc);
    base[dd + 64] = f2bf((x1 * cs + x0 * sn) * osc);
}

// ---------------- causal flash attention (v4 + T13 defer-max) ----------------
__device__ __forceinline__ void attn_stage(const unsigned short* __restrict__ kh,
                                           const unsigned short* __restrict__ vh,
                                           int kt, unsigned short* Kd, unsigned short* Vd,
                                           int w, int lane) {
    const int l4 = lane >> 4, c16 = lane & 15;
    const int l8 = lane >> 3, c8 = lane & 7;
    #pragma unroll
    for (int j = 0; j < 2; j++) {
        int R = w * 8 + j * 4;                     // K rows R..R+3
        int row = R + l4;
        int cl = c16 ^ (row & 15);                 // LDS slot (row,cs) holds chunk cs^row15
        async_ld16(kh + (size_t)(kt * 64 + row) * D_HEAD + cl * 8, Kd + R * D_HEAD);
    }
    #pragma unroll
    for (int j = 0; j < 2; j++) {
        int o8 = w * 2 + j;                        // V 8-row chunk 0..15
        int row = o8 * 8 + l8;
        int gu = (2 * c8) ^ (row & 14);            // 8B-unit swizzle, even mask keeps pairs
        async_ld16(vh + (size_t)row * T_SEQ + kt * 64 + gu * 4, Vd + o8 * 512);
    }
}

__device__ __forceinline__ void attn_tile128(const unsigned short* __restrict__ qh,
                                             const unsigned short* __restrict__ kh,
                                             const unsigned short* __restrict__ vh,
                                             unsigned short* __restrict__ attn_out,
                                             int tile, int b, int h, int w, int quad,
                                             int lo, int lane,
                                             unsigned short* Kb, unsigned short* Vb) {
    const int G = tile * 128 + 16 * w;           // this wave's 16 q-rows
    const int a = (G + 15) >> 6;                 // last needed k-tile
    const int nkt = 2 * tile + 2;
    const int tq = G + lo;

    short8 qf[4];
    #pragma unroll
    for (int ks = 0; ks < 4; ks++)
        qf[ks] = *(const short8*)(qh + (size_t)(G + lo) * D_HEAD + ks * 32 + quad * 8);

    float m_i = -1e30f, l_i = 0.f;
    f32x4 o[8];
    #pragma unroll
    for (int dt = 0; dt < 8; dt++) o[dt] = (f32x4){0.f, 0.f, 0.f, 0.f};

    attn_stage(kh, vh, 0, Kb, Vb, w, lane);
    for (int kt = 0; kt < nkt; kt++) {
        const int cur = kt & 1;
        if (kt + 1 < nkt) {
            attn_stage(kh, vh, kt + 1, Kb + (cur ^ 1) * 8192, Vb + (cur ^ 1) * 8192, w, lane);
            __builtin_amdgcn_s_waitcnt(0x3F74);   // vmcnt(4): this tile's 4 loads done
        } else {
            __builtin_amdgcn_s_waitcnt(0x3F70);   // vmcnt(0)
        }
        __asm__ volatile("" ::: "memory");
        __builtin_amdgcn_s_barrier();
        __asm__ volatile("" ::: "memory");

        if (kt <= a) {                            // wave-uniform
            const unsigned short* Kc = Kb + cur * 8192;
            const unsigned short* Vc = Vb + cur * 8192;
            // QK: S^T[key][qrow] = K . Q^T
            f32x4 s[4];
            #pragma unroll
            for (int kg = 0; kg < 4; kg++) s[kg] = (f32x4){0.f, 0.f, 0.f, 0.f};
            #pragma unroll
            for (int kg = 0; kg < 4; kg++)
                #pragma unroll
                for (int ks = 0; ks < 4; ks++) {
                    int ch = (ks * 4 + quad) ^ lo;            // row&15 == lo
                    short8 kf = *(const short8*)(Kc + (kg * 16 + lo) * D_HEAD + ch * 8);
                    s[kg] = __builtin_amdgcn_mfma_f32_16x16x32_bf16(kf, qf[ks], s[kg], 0, 0, 0);
                }

            // online softmax (exp2 domain; scale folded into Q)
            const bool msk = (kt == a);
            float mx = -1e30f;
            #pragma unroll
            for (int kg = 0; kg < 4; kg++)
                #pragma unroll
                for (int r = 0; r < 4; r++) {
                    if (msk) {
                        int key = kt * 64 + kg * 16 + quad * 4 + r;
                        if (key > tq) s[kg][r] = -1e30f;
                    }
                    mx = fmaxf(mx, s[kg][r]);
                }
            mx = fmaxf(mx, __shfl_xor(mx, 16));
            mx = fmaxf(mx, __shfl_xor(mx, 32));
            // T13 defer-max: skip O-rescale while per-tile max stays within
            // 2^8 of the kept reference (wave-uniform via __all; P <= 256,
            // fine in bf16/f32; o,l stay in units of exp2(.-m_i) either way).
            const bool resc = !__all(mx - m_i <= 8.0f);
            float mnew = resc ? fmaxf(m_i, mx) : m_i;
            float alpha = resc ? __builtin_amdgcn_exp2f(m_i - mnew) : 1.0f;
            float sm = 0.f;
            short4v pp[4];
            #pragma unroll
            for (int kg = 0; kg < 4; kg++) {
                float p0 = __builtin_amdgcn_exp2f(s[kg][0] - mnew);
                float p1 = __builtin_amdgcn_exp2f(s[kg][1] - mnew);
                float p2 = __builtin_amdgcn_exp2f(s[kg][2] - mnew);
                float p3 = __builtin_amdgcn_exp2f(s[kg][3] - mnew);
                sm += (p0 + p1) + (p2 + p3);
                union { float f; unsigned u; } c0, c1, c2, c3;
                c0.f = p0; c1.f = p1; c2.f = p2; c3.f = p3;
                union { short4v s4; unsigned u[2]; } pu;
                pu.u[0] = (c0.u >> 16) | (c1.u & 0xFFFF0000u);   // truncated bf16
                pu.u[1] = (c2.u >> 16) | (c3.u & 0xFFFF0000u);
                pp[kg] = pu.s4;
            }
            sm += __shfl_xor(sm, 16);
            sm += __shfl_xor(sm, 32);
            l_i = l_i * alpha + sm;
            m_i = mnew;

            // rescale O once (wave-uniform branch), then accumulate PV
            if (resc) {
                #pragma unroll
                for (int dt = 0; dt < 8; dt++) {
                    o[dt][0] *= alpha; o[dt][1] *= alpha;
                    o[dt][2] *= alpha; o[dt][3] *= alpha;
                }
            }
            // PV: O^T[d][qrow] += V^T . P^T   (K=16 per key-group)
            #pragma unroll
            for (int dt = 0; dt < 8; dt++) {
                f32x4 oo = o[dt];
                #pragma unroll
                for (int kg = 0; kg < 4; kg++) {
                    int un = (kg * 4 + quad) ^ (lo & 14);     // vrow&14 == lo&14
                    short4v vv = *(const short4v*)(Vc + (dt * 16 + lo) * 64 + un * 4);
                    oo = pv_mfma(vv, pp[kg], oo);
                }
                o[dt] = oo;
            }
        }
        __asm__ volatile("" ::: "memory");
        __builtin_amdgcn_s_barrier();
        __asm__ volatile("" ::: "memory");
    }

    // epilogue: O^T C-layout lane(quad,lo): d = dt*16+quad*4+r, qrow = G+lo
    float inv_l = 1.f / l_i;
    size_t base = ((size_t)b * T_SEQ + G + lo) * C_DIM + h * D_HEAD + quad * 4;
    #pragma unroll
    for (int dt = 0; dt < 8; dt++) {
        uint2 u;
        u.x = (unsigned)f2bf(o[dt][0] * inv_l) | ((unsigned)f2bf(o[dt][1] * inv_l) << 16);
        u.y = (unsigned)f2bf(o[dt][2] * inv_l) | ((unsigned)f2bf(o[dt][3] * inv_l) << 16);
        *(uint2*)(attn_out + base + dt * 16) = u;
    }
}

__global__ __launch_bounds__(512, 4) void attn_kernel(const unsigned short* __restrict__ q,
                                                      const unsigned short* __restrict__ k,
                                                      const unsigned short* __restrict__ vt,
                                                      unsigned short* __restrict__ attn_out) {
    __shared__ unsigned short Kb[2 * 64 * 128];   // 32 KB
    __shared__ unsigned short Vb[2 * 128 * 64];   // 32 KB
    const int lane = threadIdx.x & 63;
    const int w = threadIdx.x >> 6;               // 0..7
    const int quad = lane >> 4, lo = lane & 15;
    const int bid = blockIdx.x;                   // 512 blocks = 2/CU
    const int head_lin = bid & 63;                // same head => same XCD (bid%8 const)
    const int pr = bid >> 6;                      // pair index 0..7
    const int b = head_lin >> 4, h = head_lin & 15;
    const unsigned short* qh = q + (size_t)head_lin * T_SEQ * D_HEAD;
    const unsigned short* kh = k + (size_t)head_lin * T_SEQ * D_HEAD;
    const unsigned short* vh = vt + (size_t)head_lin * D_HEAD * T_SEQ;

    attn_tile128(qh, kh, vh, attn_out, pr,      b, h, w, quad, lo, lane, Kb, Vb);  // light
    attn_tile128(qh, kh, vh, attn_out, 15 - pr, b, h, w, quad, lo, lane, Kb, Vb);  // heavy
}

// ---------------- launch -----------------------------------------------------
extern "C" void kernel_launch(void* const* d_in, const int* in_sizes, int n_in,
                              void* d_out, int out_size, void* d_ws, size_t ws_size,
                              hipStream_t stream) {
    const float* x    = (const float*)d_in[0];
    const float* ln_g = (const float*)d_in[1];
    const float* ln_b = (const float*)d_in[2];
    const float* Wq   = (const float*)d_in[3];
    const float* bq   = (const float*)d_in[4];
    const float* Wk   = (const float*)d_in[5];
    const float* bk   = (const float*)d_in[6];
    const float* Wv   = (const float*)d_in[7];
    const float* bv   = (const float*)d_in[8];
    const float* Wo   = (const float*)d_in[9];
    const float* bo   = (const float*)d_in[10];
    float* out = (float*)d_out;

    char* ws = (char*)d_ws;
    const size_t SZ = (size_t)M_ROWS * C_DIM * 2;        // 33,554,432 bytes
    unsigned short* nx  = (unsigned short*)(ws);
    unsigned short* wt  = (unsigned short*)(ws + SZ);    // 4 x 2048 x 2048 bf16
    unsigned short* qb  = (unsigned short*)(ws + 2 * SZ);
    unsigned short* kb  = (unsigned short*)(ws + 3 * SZ);
    unsigned short* vtb = (unsigned short*)(ws + 4 * SZ);
    unsigned short* at  = (unsigned short*)(ws + 5 * SZ);

    static bool lds_inited = false;
    if (!lds_inited) {
        hipFuncSetAttribute((const void*)gemm_qkv,
                            hipFuncAttributeMaxDynamicSharedMemorySize, 131072);
        hipFuncSetAttribute((const void*)gemm_out,
                            hipFuncAttributeMaxDynamicSharedMemorySize, 131072);
        lds_inited = true;
    }

    wcast_kernel<<<dim3(64, 64, 4), dim3(32, 8), 0, stream>>>(Wq, Wk, Wv, Wo, wt);
    ln_kernel<<<M_ROWS, 256, 0, stream>>>(x, ln_g, ln_b, nx);
    gemm_qkv<<<768, 512, 131072, stream>>>(nx, wt, bq, bk, bv, qb, kb, vtb);
    rope_kernel<<<dim3((B_NUM * H_NUM * T_SEQ * 64) / 256, 2), 256, 0, stream>>>(qb, kb);
    attn_kernel<<<512, 512, 0, stream>>>(qb, kb, vtb, at);
    gemm_out<<<256, 512, 131072, stream>>>(at, wt + (size_t)3 * C_DIM * C_DIM, bo, x, out);
}

// Round 8
// 611.868 us; speedup vs baseline: 1.2998x; 1.0165x over previous
//
#include <hip/hip_runtime.h>

typedef short short8 __attribute__((ext_vector_type(8)));
typedef short short4v __attribute__((ext_vector_type(4)));
typedef float f32x4 __attribute__((ext_vector_type(4)));

#define T_SEQ 2048
#define C_DIM 2048
#define H_NUM 16
#define D_HEAD 128
#define B_NUM 4
#define M_ROWS (B_NUM * T_SEQ)   // 8192

__device__ __forceinline__ unsigned short f2bf(float f) {
    union { float f; unsigned u; } v; v.f = f;
    unsigned r = v.u + 0x7FFFu + ((v.u >> 16) & 1u);
    return (unsigned short)(r >> 16);
}
__device__ __forceinline__ float bf2f(unsigned short u) {
    union { unsigned u; float f; } v; v.u = ((unsigned)u) << 16;
    return v.f;
}

// async global->LDS, 16B per lane; lds ptr wave-uniform (HW adds lane*16)
__device__ __forceinline__ void async_ld16(const unsigned short* g, unsigned short* l) {
    __builtin_amdgcn_global_load_lds(
        (const __attribute__((address_space(1))) unsigned int*)g,
        (__attribute__((address_space(3))) unsigned int*)l,
        16, 0, 0);
}

__device__ __forceinline__ f32x4 pv_mfma(short4v v, short4v p, f32x4 c) {
#if __has_builtin(__builtin_amdgcn_mfma_f32_16x16x16bf16_1k)
    return __builtin_amdgcn_mfma_f32_16x16x16bf16_1k(v, p, c, 0, 0, 0);
#else
    short8 vf = {v[0], v[1], v[2], v[3], 0, 0, 0, 0};
    short8 pf = {p[0], p[1], p[2], p[3], 0, 0, 0, 0};
    return __builtin_amdgcn_mfma_f32_16x16x32_bf16(vf, pf, c, 0, 0, 0);
#endif
}

// ---------------- weight cast + transpose: wt[w][n][k] = W_w[k][n] (bf16) ----
__global__ __launch_bounds__(256) void wcast_kernel(const float* __restrict__ W0,
                                                    const float* __restrict__ W1,
                                                    const float* __restrict__ W2,
                                                    const float* __restrict__ W3,
                                                    unsigned short* __restrict__ wt) {
    __shared__ float tile[32][33];
    const float* W = (blockIdx.z == 0) ? W0 : (blockIdx.z == 1) ? W1 : (blockIdx.z == 2) ? W2 : W3;
    unsigned short* out = wt + (size_t)blockIdx.z * C_DIM * C_DIM;
    int tx = threadIdx.x, ty = threadIdx.y;      // block (32, 8)
    int n0 = blockIdx.x * 32, k0 = blockIdx.y * 32;
    #pragma unroll
    for (int j = 0; j < 32; j += 8)
        tile[ty + j][tx] = W[(size_t)(k0 + ty + j) * C_DIM + n0 + tx];
    __syncthreads();
    #pragma unroll
    for (int j = 0; j < 32; j += 8)
        out[(size_t)(n0 + ty + j) * C_DIM + k0 + tx] = f2bf(tile[tx][ty + j]);
}

// ---------------- LayerNorm -> bf16 ----------------------------------------
__global__ __launch_bounds__(256) void ln_kernel(const float* __restrict__ x,
                                                 const float* __restrict__ g,
                                                 const float* __restrict__ bta,
                                                 unsigned short* __restrict__ nx) {
    int row = blockIdx.x;
    int tid = threadIdx.x;
    const float* xr = x + (size_t)row * C_DIM;
    float4 v0 = *(const float4*)(xr + tid * 8);
    float4 v1 = *(const float4*)(xr + tid * 8 + 4);
    float s = v0.x + v0.y + v0.z + v0.w + v1.x + v1.y + v1.z + v1.w;
    float q = v0.x * v0.x + v0.y * v0.y + v0.z * v0.z + v0.w * v0.w +
              v1.x * v1.x + v1.y * v1.y + v1.z * v1.z + v1.w * v1.w;
    #pragma unroll
    for (int m = 32; m; m >>= 1) { s += __shfl_xor(s, m); q += __shfl_xor(q, m); }
    __shared__ float red[2][4];
    int wave = tid >> 6, lane = tid & 63;
    if (lane == 0) { red[0][wave] = s; red[1][wave] = q; }
    __syncthreads();
    s = red[0][0] + red[0][1] + red[0][2] + red[0][3];
    q = red[1][0] + red[1][1] + red[1][2] + red[1][3];
    float mu = s * (1.0f / C_DIM);
    float var = q * (1.0f / C_DIM) - mu * mu;
    float rstd = rsqrtf(var + 1e-5f);
    float4 g0 = *(const float4*)(g + tid * 8);
    float4 g1 = *(const float4*)(g + tid * 8 + 4);
    float4 b0 = *(const float4*)(bta + tid * 8);
    float4 b1 = *(const float4*)(bta + tid * 8 + 4);
    unsigned short o[8];
    o[0] = f2bf((v0.x - mu) * rstd * g0.x + b0.x);
    o[1] = f2bf((v0.y - mu) * rstd * g0.y + b0.y);
    o[2] = f2bf((v0.z - mu) * rstd * g0.z + b0.z);
    o[3] = f2bf((v0.w - mu) * rstd * g0.w + b0.w);
    o[4] = f2bf((v1.x - mu) * rstd * g1.x + b1.x);
    o[5] = f2bf((v1.y - mu) * rstd * g1.y + b1.y);
    o[6] = f2bf((v1.z - mu) * rstd * g1.z + b1.z);
    o[7] = f2bf((v1.w - mu) * rstd * g1.w + b1.w);
    uint4 pk;
    pk.x = (unsigned)o[0] | ((unsigned)o[1] << 16);
    pk.y = (unsigned)o[2] | ((unsigned)o[3] << 16);
    pk.z = (unsigned)o[4] | ((unsigned)o[5] << 16);
    pk.w = (unsigned)o[6] | ((unsigned)o[7] << 16);
    *(uint4*)(nx + (size_t)row * C_DIM + tid * 8) = pk;
}

// ============================================================================
// 256x256 / BK=64 / 8-wave GEMM core, TWO barriers per K-tile.
// (R3-benched structure, verified best: gemm_qkv 235.8us, 0 bank conflicts.)
//
// R8 change: wave->column mapping is n = colBase + qn*128 + ni*64 + wn*16 + lo
// (bit 6 of n now comes from ni, not wn) so that a thread's acc[..][0][r] and
// acc[..][1][r] hold the RoPE rotation pair (d, d+64) of the SAME head ->
// RoPE fuses into the gemm_qkv epilogue (rope_kernel deleted; saves ~128MB
// HBM round-trip). Swizzle validity preserved: row&7 == lo&7 still holds
// (16*wn, 64*ni, 128*qn all ≡ 0 mod 8); only RDB's ni-stride changes.
//
// LDS (dynamic, 128 KiB): 2 buffers x { A[256][64], B[256][64] } bf16.
//   Regions (elements): Ah0=0, Ah1=8192, Bh0=16384, Bh1=24576.
//   XOR chunk swizzle: 16B-chunk c of row r at slot c^(r&7); global source
//   pre-swizzled (global_load_lds dest is linear).
// Per tile t (reads from buf[t&1]):
//   rd af0,bf0,bf1 (16 ds_read); stage (t+1).Ah1/Bh1 -> buf[t+1];
//   MFMA (0,0),(0,1); rd af1 (Ah1 - disjoint from staged regions);
//   BAR#1; stage (t+2).Ah0/Bh0 -> buf[t];
//   MFMA (1,1),(1,0); vmcnt(4) (or 0 at tail); BAR#2.
// Hazard notes (R6 lesson: vmcnt is PER-WAVE; any LDS read of a region
// DMA-written by another wave must be preceded by wait->barrier in all
// waves): every read here happens after the boundary barrier that postdates
// all waves' vmcnt(4) -> tile t fully resident.
// ============================================================================

#define GBK 64
#define GNT (C_DIM / GBK)        // 32 K-tiles

#define GFENCE __asm__ volatile("" ::: "memory")
#define GBAR do { GFENCE; __builtin_amdgcn_s_barrier(); GFENCE; } while (0)

__device__ __forceinline__ void mfma16(const short8 af[4][2], const short8 bf[2][2],
                                       f32x4 acc[4][2]) {
    __builtin_amdgcn_s_setprio(1);
    #pragma unroll
    for (int mi = 0; mi < 4; mi++)
        #pragma unroll
        for (int ni = 0; ni < 2; ni++)
            #pragma unroll
            for (int ks = 0; ks < 2; ks++)
                acc[mi][ni] = __builtin_amdgcn_mfma_f32_16x16x32_bf16(af[mi][ks], bf[ni][ks],
                                                                      acc[mi][ni], 0, 0, 0);
    __builtin_amdgcn_s_setprio(0);
}

__device__ __forceinline__ void gemm_core256(const unsigned short* __restrict__ A,
                                             const unsigned short* __restrict__ Bt,
                                             unsigned short* lds,
                                             int rowBase, int colBase,
                                             f32x4 acc[2][2][4][2]) {
    const int tid = threadIdx.x;
    const int lane = tid & 63, w = tid >> 6;
    const int quad = lane >> 4, lo = lane & 15;
    const int wm = w >> 2, wn = w & 3;

    // precomputed LDS read bases (elements)
    const int swz8 = (quad ^ (lo & 7)) * 8;
    const int aoff = (wm * 64 + lo) * 64 + swz8;
    const int boff = (wn * 16 + lo) * 64 + swz8;     // R8: wn*16 (bit6 -> ni)

    // precomputed per-lane global stage offsets (elements) + LDS dest offsets
    const int r8 = lane >> 3, c8 = lane & 7;
    const int goff0 = (w * 8 + r8) * C_DIM + ((c8 ^ r8) << 3);
    const int goff1 = (64 + w * 8 + r8) * C_DIM + ((c8 ^ r8) << 3);
    const int ldst0 = (w * 8) * 64;
    const int ldst1 = (64 + w * 8) * 64;

    unsigned short* const L0 = lds;
    unsigned short* const L1 = lds + 32768;

    const unsigned short* gA0 = A + (size_t)rowBase * C_DIM;
    const unsigned short* gA1 = gA0 + (size_t)128 * C_DIM;
    const unsigned short* gB0 = Bt + (size_t)colBase * C_DIM;
    const unsigned short* gB1 = gB0 + (size_t)128 * C_DIM;

#define STAGE(gbase, lregion) do { \
        async_ld16((gbase) + goff0, (lregion) + ldst0); \
        async_ld16((gbase) + goff1, (lregion) + ldst1); \
    } while (0)

#define RDA(As, qm, dst) do { \
        _Pragma("unroll") \
        for (int mi = 0; mi < 4; mi++) { \
            dst[mi][0] = *(const short8*)((As) + (((qm) * 8192 + mi * 1024 + aoff))); \
            dst[mi][1] = *(const short8*)((As) + (((qm) * 8192 + mi * 1024 + aoff) ^ 32)); \
        } \
    } while (0)

#define RDB(Bs, qn, dst) do { \
        _Pragma("unroll") \
        for (int ni = 0; ni < 2; ni++) { \
            dst[ni][0] = *(const short8*)((Bs) + (((qn) * 8192 + ni * 4096 + boff))); \
            dst[ni][1] = *(const short8*)((Bs) + (((qn) * 8192 + ni * 4096 + boff) ^ 32)); \
        } \
    } while (0)

    // prologue: t0 all 4 halves + t1.{Ah0,Bh0}; vmcnt(4) -> t0 resident,
    // t1's two halves stay in flight (steady-state queue shape).
    STAGE(gA0,      L0);             // (0).Ah0
    STAGE(gB0,      L0 + 16384);     // (0).Bh0
    STAGE(gA1,      L0 + 8192);      // (0).Ah1
    STAGE(gB1,      L0 + 24576);     // (0).Bh1
    STAGE(gA0 + 64, L1);             // (1).Ah0
    STAGE(gB0 + 64, L1 + 16384);     // (1).Bh0
    __builtin_amdgcn_s_waitcnt(0x3F74);            // vmcnt(4)
    GBAR;

    for (int t = 0; t < GNT; ++t) {
        const unsigned short* As = (t & 1) ? L1 : L0;
        const unsigned short* Bs = As + 16384;
        unsigned short* Ln = (t & 1) ? L0 : L1;    // buf[(t+1)&1]
        unsigned short* Lc = (t & 1) ? L1 : L0;    // buf[t&1]
        short8 af[4][2], bf0[2][2], bf1[2][2];

        // ---- first half: all reads for quadrants (0,*), stage next-buf ----
        RDA(As, 0, af);
        RDB(Bs, 0, bf0);
        RDB(Bs, 1, bf1);
        if (t + 1 < GNT) {
            STAGE(gA1 + (t + 1) * GBK, Ln + 8192);   // (t+1).Ah1
            STAGE(gB1 + (t + 1) * GBK, Ln + 24576);  // (t+1).Bh1
        }
        mfma16(af, bf0, acc[0][0]);
        mfma16(af, bf1, acc[0][1]);
        RDA(As, 1, af);                              // Ah1: disjoint from staged regions
        GBAR;                                        // BAR#1

        // ---- second half: stage cur-buf (t+2), finish quadrants (1,*) ----
        if (t + 2 < GNT) {
            STAGE(gA0 + (t + 2) * GBK, Lc);          // (t+2).Ah0
            STAGE(gB0 + (t + 2) * GBK, Lc + 16384);  // (t+2).Bh0
        }
        mfma16(af, bf1, acc[1][1]);
        mfma16(af, bf0, acc[1][0]);

        // ---- boundary: tile t+1 resident; keep (t+2) halves in flight ----
        if (t + 2 < GNT) __builtin_amdgcn_s_waitcnt(0x3F74);   // vmcnt(4)
        else             __builtin_amdgcn_s_waitcnt(0x3F70);   // vmcnt(0)
        GBAR;
    }
#undef STAGE
#undef RDA
#undef RDB
}

// ---------------- fused QKV GEMM (N = 6144) + fused RoPE --------------------
__global__ __launch_bounds__(512, 2) void gemm_qkv(const unsigned short* __restrict__ A,
                                                   const unsigned short* __restrict__ Bt,
                                                   const float* __restrict__ bq,
                                                   const float* __restrict__ bk,
                                                   const float* __restrict__ bv,
                                                   unsigned short* __restrict__ qb,
                                                   unsigned short* __restrict__ kb,
                                                   unsigned short* __restrict__ vtb) {
    extern __shared__ unsigned short ldsbuf[];
    f32x4 acc[2][2][4][2] = {};
    const int bid = blockIdx.x;                   // 768 blocks, 768%8==0
    const int b2 = (bid & 7) * 96 + (bid >> 3);   // bijective XCD swizzle
    const int rowBase = (b2 / 24) * 256;
    const int colBase = (b2 % 24) * 256;
    gemm_core256(A, Bt, ldsbuf, rowBase, colBase, acc);

    const int lane = threadIdx.x & 63, w = threadIdx.x >> 6;
    const int quad = lane >> 4, lo = lane & 15;
    const int wm = w >> 2, wn = w & 3;
    const int which = colBase >> 11;              // 256-tiles never straddle 2048
    const float* bias = (which == 0) ? bq : (which == 1) ? bk : bv;
    const int d0 = wn * 16 + lo;                  // rope dim (< 64), lane-const
    const float inv = exp2f((float)d0 * (-13.287712379549449f / 64.0f));
    const float osc = (which == 0) ? 0.12751736f : 1.0f;  // log2(e)/sqrt(128)
    #pragma unroll
    for (int qm = 0; qm < 2; qm++)
        #pragma unroll
        for (int qn = 0; qn < 2; qn++) {
            const int c0 = (colBase + qn * 128 + wn * 16 + lo) & (C_DIM - 1);
            const int h = c0 >> 7;                // d = d0 (ni=0) / d0+64 (ni=1)
            const float bs0 = bias[c0];
            const float bs1 = bias[c0 + 64];
            #pragma unroll
            for (int mi = 0; mi < 4; mi++)
                #pragma unroll
                for (int r = 0; r < 4; r++) {
                    int m = rowBase + qm * 128 + wm * 64 + mi * 16 + quad * 4 + r;
                    int bb = m >> 11, tt = m & (T_SEQ - 1);
                    float x0 = acc[qm][qn][mi][0][r] + bs0;
                    float x1 = acc[qm][qn][mi][1][r] + bs1;
                    if (which == 2) {
                        size_t vb = (size_t)((bb * H_NUM + h) * D_HEAD) * T_SEQ + tt;
                        vtb[vb + (size_t)d0 * T_SEQ] = f2bf(x0);
                        vtb[vb + (size_t)(d0 + 64) * T_SEQ] = f2bf(x1);
                    } else {
                        float ang = (float)tt * inv;
                        float sn = __sinf(ang), cs = __cosf(ang);
                        unsigned short y0 = f2bf((x0 * cs - x1 * sn) * osc);
                        unsigned short y1 = f2bf((x1 * cs + x0 * sn) * osc);
                        unsigned short* dst = (which == 1) ? kb : qb;
                        size_t qk = (size_t)((bb * H_NUM + h) * T_SEQ + tt) * D_HEAD;
                        dst[qk + d0] = y0;
                        dst[qk + d0 + 64] = y1;
                    }
                }
        }
}

// ---------------- output GEMM + bias + residual -----------------------------
__global__ __launch_bounds__(512, 2) void gemm_out(const unsigned short* __restrict__ A,
                                                   const unsigned short* __restrict__ Bt,
                                                   const float* __restrict__ bo,
                                                   const float* __restrict__ x,
                                                   float* __restrict__ out) {
    extern __shared__ unsigned short ldsbuf[];
    f32x4 acc[2][2][4][2] = {};
    const int bid = blockIdx.x;                   // 256 blocks
    const int b2 = (bid & 7) * 32 + (bid >> 3);
    const int rowBase = (b2 / 8) * 256;
    const int colBase = (b2 % 8) * 256;
    gemm_core256(A, Bt, ldsbuf, rowBase, colBase, acc);

    const int lane = threadIdx.x & 63, w = threadIdx.x >> 6;
    const int quad = lane >> 4, lo = lane & 15;
    const int wm = w >> 2, wn = w & 3;
    #pragma unroll
    for (int qm = 0; qm < 2; qm++)
        #pragma unroll
        for (int qn = 0; qn < 2; qn++)
            #pragma unroll
            for (int mi = 0; mi < 4; mi++)
                #pragma unroll
                for (int ni = 0; ni < 2; ni++) {
                    int n = colBase + qn * 128 + ni * 64 + wn * 16 + lo;  // R8 map
                    float bsv = bo[n];
                    #pragma unroll
                    for (int r = 0; r < 4; r++) {
                        int m = rowBase + qm * 128 + wm * 64 + mi * 16 + quad * 4 + r;
                        size_t idx = (size_t)m * C_DIM + n;
                        out[idx] = x[idx] + acc[qm][qn][mi][ni][r] + bsv;
                    }
                }
}

// ---------------- causal flash attention (v4 + T13 defer-max) ----------------
__device__ __forceinline__ void attn_stage(const unsigned short* __restrict__ kh,
                                           const unsigned short* __restrict__ vh,
                                           int kt, unsigned short* Kd, unsigned short* Vd,
                                           int w, int lane) {
    const int l4 = lane >> 4, c16 = lane & 15;
    const int l8 = lane >> 3, c8 = lane & 7;
    #pragma unroll
    for (int j = 0; j < 2; j++) {
        int R = w * 8 + j * 4;                     // K rows R..R+3
        int row = R + l4;
        int cl = c16 ^ (row & 15);                 // LDS slot (row,cs) holds chunk cs^row15
        async_ld16(kh + (size_t)(kt * 64 + row) * D_HEAD + cl * 8, Kd + R * D_HEAD);
    }
    #pragma unroll
    for (int j = 0; j < 2; j++) {
        int o8 = w * 2 + j;                        // V 8-row chunk 0..15
        int row = o8 * 8 + l8;
        int gu = (2 * c8) ^ (row & 14);            // 8B-unit swizzle, even mask keeps pairs
        async_ld16(vh + (size_t)row * T_SEQ + kt * 64 + gu * 4, Vd + o8 * 512);
    }
}

__device__ __forceinline__ void attn_tile128(const unsigned short* __restrict__ qh,
                                             const unsigned short* __restrict__ kh,
                                             const unsigned short* __restrict__ vh,
                                             unsigned short* __restrict__ attn_out,
                                             int tile, int b, int h, int w, int quad,
                                             int lo, int lane,
                                             unsigned short* Kb, unsigned short* Vb) {
    const int G = tile * 128 + 16 * w;           // this wave's 16 q-rows
    const int a = (G + 15) >> 6;                 // last needed k-tile
    const int nkt = 2 * tile + 2;
    const int tq = G + lo;

    short8 qf[4];
    #pragma unroll
    for (int ks = 0; ks < 4; ks++)
        qf[ks] = *(const short8*)(qh + (size_t)(G + lo) * D_HEAD + ks * 32 + quad * 8);

    float m_i = -1e30f, l_i = 0.f;
    f32x4 o[8];
    #pragma unroll
    for (int dt = 0; dt < 8; dt++) o[dt] = (f32x4){0.f, 0.f, 0.f, 0.f};

    attn_stage(kh, vh, 0, Kb, Vb, w, lane);
    for (int kt = 0; kt < nkt; kt++) {
        const int cur = kt & 1;
        if (kt + 1 < nkt) {
            attn_stage(kh, vh, kt + 1, Kb + (cur ^ 1) * 8192, Vb + (cur ^ 1) * 8192, w, lane);
            __builtin_amdgcn_s_waitcnt(0x3F74);   // vmcnt(4): this tile's 4 loads done
        } else {
            __builtin_amdgcn_s_waitcnt(0x3F70);   // vmcnt(0)
        }
        __asm__ volatile("" ::: "memory");
        __builtin_amdgcn_s_barrier();
        __asm__ volatile("" ::: "memory");

        if (kt <= a) {                            // wave-uniform
            const unsigned short* Kc = Kb + cur * 8192;
            const unsigned short* Vc = Vb + cur * 8192;
            // QK: S^T[key][qrow] = K . Q^T
            f32x4 s[4];
            #pragma unroll
            for (int kg = 0; kg < 4; kg++) s[kg] = (f32x4){0.f, 0.f, 0.f, 0.f};
            #pragma unroll
            for (int kg = 0; kg < 4; kg++)
                #pragma unroll
                for (int ks = 0; ks < 4; ks++) {
                    int ch = (ks * 4 + quad) ^ lo;            // row&15 == lo
                    short8 kf = *(const short8*)(Kc + (kg * 16 + lo) * D_HEAD + ch * 8);
                    s[kg] = __builtin_amdgcn_mfma_f32_16x16x32_bf16(kf, qf[ks], s[kg], 0, 0, 0);
                }

            // online softmax (exp2 domain; scale folded into Q)
            const bool msk = (kt == a);
            float mx = -1e30f;
            #pragma unroll
            for (int kg = 0; kg < 4; kg++)
                #pragma unroll
                for (int r = 0; r < 4; r++) {
                    if (msk) {
                        int key = kt * 64 + kg * 16 + quad * 4 + r;
                        if (key > tq) s[kg][r] = -1e30f;
                    }
                    mx = fmaxf(mx, s[kg][r]);
                }
            mx = fmaxf(mx, __shfl_xor(mx, 16));
            mx = fmaxf(mx, __shfl_xor(mx, 32));
            // T13 defer-max: skip O-rescale while per-tile max stays within
            // 2^8 of the kept reference (wave-uniform via __all; P <= 256,
            // fine in bf16/f32; o,l stay in units of exp2(.-m_i) either way).
            const bool resc = !__all(mx - m_i <= 8.0f);
            float mnew = resc ? fmaxf(m_i, mx) : m_i;
            float alpha = resc ? __builtin_amdgcn_exp2f(m_i - mnew) : 1.0f;
            float sm = 0.f;
            short4v pp[4];
            #pragma unroll
            for (int kg = 0; kg < 4; kg++) {
                float p0 = __builtin_amdgcn_exp2f(s[kg][0] - mnew);
                float p1 = __builtin_amdgcn_exp2f(s[kg][1] - mnew);
                float p2 = __builtin_amdgcn_exp2f(s[kg][2] - mnew);
                float p3 = __builtin_amdgcn_exp2f(s[kg][3] - mnew);
                sm += (p0 + p1) + (p2 + p3);
                union { float f; unsigned u; } c0, c1, c2, c3;
                c0.f = p0; c1.f = p1; c2.f = p2; c3.f = p3;
                union { short4v s4; unsigned u[2]; } pu;
                pu.u[0] = (c0.u >> 16) | (c1.u & 0xFFFF0000u);   // truncated bf16
                pu.u[1] = (c2.u >> 16) | (c3.u & 0xFFFF0000u);
                pp[kg] = pu.s4;
            }
            sm += __shfl_xor(sm, 16);
            sm += __shfl_xor(sm, 32);
            l_i = l_i * alpha + sm;
            m_i = mnew;

            // rescale O once (wave-uniform branch), then accumulate PV
            if (resc) {
                #pragma unroll
                for (int dt = 0; dt < 8; dt++) {
                    o[dt][0] *= alpha; o[dt][1] *= alpha;
                    o[dt][2] *= alpha; o[dt][3] *= alpha;
                }
            }
            // PV: O^T[d][qrow] += V^T . P^T   (K=16 per key-group)
            #pragma unroll
            for (int dt = 0; dt < 8; dt++) {
                f32x4 oo = o[dt];
                #pragma unroll
                for (int kg = 0; kg < 4; kg++) {
                    int un = (kg * 4 + quad) ^ (lo & 14);     // vrow&14 == lo&14
                    short4v vv = *(const short4v*)(Vc + (dt * 16 + lo) * 64 + un * 4);
                    oo = pv_mfma(vv, pp[kg], oo);
                }
                o[dt] = oo;
            }
        }
        __asm__ volatile("" ::: "memory");
        __builtin_amdgcn_s_barrier();
        __asm__ volatile("" ::: "memory");
    }

    // epilogue: O^T C-layout lane(quad,lo): d = dt*16+quad*4+r, qrow = G+lo
    float inv_l = 1.f / l_i;
    size_t base = ((size_t)b * T_SEQ + G + lo) * C_DIM + h * D_HEAD + quad * 4;
    #pragma unroll
    for (int dt = 0; dt < 8; dt++) {
        uint2 u;
        u.x = (unsigned)f2bf(o[dt][0] * inv_l) | ((unsigned)f2bf(o[dt][1] * inv_l) << 16);
        u.y = (unsigned)f2bf(o[dt][2] * inv_l) | ((unsigned)f2bf(o[dt][3] * inv_l) << 16);
        *(uint2*)(attn_out + base + dt * 16) = u;
    }
}

__global__ __launch_bounds__(512, 4) void attn_kernel(const unsigned short* __restrict__ q,
                                                      const unsigned short* __restrict__ k,
                                                      const unsigned short* __restrict__ vt,
                                                      unsigned short* __restrict__ attn_out) {
    __shared__ unsigned short Kb[2 * 64 * 128];   // 32 KB
    __shared__ unsigned short Vb[2 * 128 * 64];   // 32 KB
    const int lane = threadIdx.x & 63;
    const int w = threadIdx.x >> 6;               // 0..7
    const int quad = lane >> 4, lo = lane & 15;
    const int bid = blockIdx.x;                   // 512 blocks = 2/CU
    const int head_lin = bid & 63;                // same head => same XCD (bid%8 const)
    const int pr = bid >> 6;                      // pair index 0..7
    const int b = head_lin >> 4, h = head_lin & 15;
    const unsigned short* qh = q + (size_t)head_lin * T_SEQ * D_HEAD;
    const unsigned short* kh = k + (size_t)head_lin * T_SEQ * D_HEAD;
    const unsigned short* vh = vt + (size_t)head_lin * D_HEAD * T_SEQ;

    attn_tile128(qh, kh, vh, attn_out, pr,      b, h, w, quad, lo, lane, Kb, Vb);  // light
    attn_tile128(qh, kh, vh, attn_out, 15 - pr, b, h, w, quad, lo, lane, Kb, Vb);  // heavy
}

// ---------------- launch -----------------------------------------------------
extern "C" void kernel_launch(void* const* d_in, const int* in_sizes, int n_in,
                              void* d_out, int out_size, void* d_ws, size_t ws_size,
                              hipStream_t stream) {
    const float* x    = (const float*)d_in[0];
    const float* ln_g = (const float*)d_in[1];
    const float* ln_b = (const float*)d_in[2];
    const float* Wq   = (const float*)d_in[3];
    const float* bq   = (const float*)d_in[4];
    const float* Wk   = (const float*)d_in[5];
    const float* bk   = (const float*)d_in[6];
    const float* Wv   = (const float*)d_in[7];
    const float* bv   = (const float*)d_in[8];
    const float* Wo   = (const float*)d_in[9];
    const float* bo   = (const float*)d_in[10];
    float* out = (float*)d_out;

    char* ws = (char*)d_ws;
    const size_t SZ = (size_t)M_ROWS * C_DIM * 2;        // 33,554,432 bytes
    unsigned short* nx  = (unsigned short*)(ws);
    unsigned short* wt  = (unsigned short*)(ws + SZ);    // 4 x 2048 x 2048 bf16
    unsigned short* qb  = (unsigned short*)(ws + 2 * SZ);
    unsigned short* kb  = (unsigned short*)(ws + 3 * SZ);
    unsigned short* vtb = (unsigned short*)(ws + 4 * SZ);
    unsigned short* at  = (unsigned short*)(ws + 5 * SZ);

    static bool lds_inited = false;
    if (!lds_inited) {
        hipFuncSetAttribute((const void*)gemm_qkv,
                            hipFuncAttributeMaxDynamicSharedMemorySize, 131072);
        hipFuncSetAttribute((const void*)gemm_out,
                            hipFuncAttributeMaxDynamicSharedMemorySize, 131072);
        lds_inited = true;
    }

    wcast_kernel<<<dim3(64, 64, 4), dim3(32, 8), 0, stream>>>(Wq, Wk, Wv, Wo, wt);
    ln_kernel<<<M_ROWS, 256, 0, stream>>>(x, ln_g, ln_b, nx);
    gemm_qkv<<<768, 512, 131072, stream>>>(nx, wt, bq, bk, bv, qb, kb, vtb);
    attn_kernel<<<512, 512, 0, stream>>>(qb, kb, vtb, at);
    gemm_out<<<256, 512, 131072, stream>>>(at, wt + (size_t)3 * C_DIM * C_DIM, bo, x, out);
}